// Round 1
// baseline (557.645 us; speedup 1.0000x reference)
//
#include <hip/hip_runtime.h>
#include <hip/hip_bf16.h>
#include <stdint.h>

#define NUM_USERS 100000
#define NUM_ITEMS 50000
#define N_NODES   150000
#define LATENT    64
#define SBERT     384
#define N_EDGES   2000000
#define OUT_OFF   (N_NODES * LATENT)   // out = d_out + OUT_OFF
#define NBUCK     586                  // ceil(150000 / 256), 256 nodes per bucket
#define BCAP      4096                 // fixed bin capacity per bucket (mean 3413, sigma 58)
#define EPB       2048                 // edges per k_bin block (977 blocks: occupancy fix)
#define YHALF     (N_NODES * 32)       // elements per feature-half plane of y

typedef __hip_bfloat16 bf16;

__device__ __forceinline__ int ufl(int v) { return __builtin_amdgcn_readfirstlane(v); }

// ---------- zero bucket counters ----------
__global__ void k_zero_bcnt(int* __restrict__ bcnt) {
    int i = blockIdx.x * 256 + threadIdx.x;
    if (i < NBUCK) bcnt[i] = 0;
}

// ---------- binning: bucket edges by dst>>8 into fixed-capacity bins ----------
__global__ __launch_bounds__(256) void k_bin(const int* __restrict__ src,
                                             const int* __restrict__ dst,
                                             int* __restrict__ bcnt,
                                             unsigned* __restrict__ bin) {
    __shared__ int hist[NBUCK];
    __shared__ int base[NBUCK];
    const int tid = threadIdx.x;
    for (int i = tid; i < NBUCK; i += 256) hist[i] = 0;
    __syncthreads();
    const int e0 = blockIdx.x * EPB;
    const int e1 = min(e0 + EPB, N_EDGES);
    for (int e = e0 + tid; e < e1; e += 256)
        atomicAdd(&hist[dst[e] >> 8], 1);
    __syncthreads();
    for (int i = tid; i < NBUCK; i += 256) {
        int c = hist[i];
        base[i] = c ? atomicAdd(&bcnt[i], c) : 0;
        hist[i] = 0;                       // reuse as local cursor
    }
    __syncthreads();
    for (int e = e0 + tid; e < e1; e += 256) {
        int d = dst[e];
        int b = d >> 8;
        int p = base[b] + atomicAdd(&hist[b], 1);
        bin[(size_t)b * BCAP + p] = (unsigned)src[e] | ((unsigned)(d & 255) << 18);  // src < 2^18
    }
}

// ---------- exclusive scan of 586 bucket counts (single block) ----------
__global__ __launch_bounds__(1024) void k_bscan(const int* __restrict__ bcnt,
                                                int* __restrict__ bbase) {
    __shared__ int sm[1024];
    int tid = threadIdx.x;
    int v = (tid < NBUCK) ? bcnt[tid] : 0;
    sm[tid] = v;
    __syncthreads();
    for (int off = 1; off < 1024; off <<= 1) {
        int t = (tid >= off) ? sm[tid - off] : 0;
        __syncthreads();
        sm[tid] += t;
        __syncthreads();
    }
    if (tid <= NBUCK) bbase[tid] = (tid == 0) ? 0 : sm[tid - 1];
}

// ---------- per-bucket: degree histogram -> rp, dis; scatter src-only CSR ----------
__global__ __launch_bounds__(256) void k_build(const unsigned* __restrict__ bin,
                                               const int* __restrict__ bcnt,
                                               const int* __restrict__ bbase,
                                               int* __restrict__ rp,
                                               float* __restrict__ dis,
                                               int* __restrict__ cws) {
    __shared__ int h[256];
    __shared__ int lc[256];
    const int tid   = threadIdx.x;
    const int b     = blockIdx.x;
    const int nbase = b << 8;
    const unsigned* mybin = bin + (size_t)b * BCAP;
    h[tid] = 0;
    __syncthreads();
    const int cnt  = bcnt[b];
    const int base = bbase[b];
    for (int i = tid; i < cnt; i += 256)
        atomicAdd(&h[mybin[i] >> 18], 1);
    __syncthreads();
    int v = h[tid];
    // block exclusive scan of h
    __shared__ int sm[256];
    sm[tid] = v;
    __syncthreads();
    for (int off = 1; off < 256; off <<= 1) {
        int t = (tid >= off) ? sm[tid - off] : 0;
        __syncthreads();
        sm[tid] += t;
        __syncthreads();
    }
    int excl = sm[tid] - v;
    int n = nbase + tid;
    if (n < N_NODES) {
        rp[n]  = base + excl;
        dis[n] = (v > 0) ? rsqrtf((float)v) : 0.0f;
    }
    lc[tid] = base + excl;
    if (b == NBUCK - 1 && tid == 0) rp[N_NODES] = N_EDGES;
    __syncthreads();
    for (int i = tid; i < cnt; i += 256) {
        unsigned rec = mybin[i];
        int dl = rec >> 18;
        int pos = atomicAdd(&lc[dl], 1);
        cws[pos] = (int)(rec & 0x3FFFF);
    }
}

// ---------- copy user_emb into emb0 + acc (fp32) and y0 = bf16(dis*u), split-half layout ----------
__global__ void k_copy_user(const float* __restrict__ u, const float* __restrict__ dis,
                            float* __restrict__ out, bf16* __restrict__ y) {
    int i = blockIdx.x * 256 + threadIdx.x;
    if (i < NUM_USERS * LATENT) {
        float v = u[i];
        out[i] = v;                      // emb0
        out[OUT_OFF + i] = v;            // acc init
        int n = i >> 6;                  // wave-uniform
        int f = i & 63;
        float d = dis[n];
        // y layout: [half][node][32]
        y[(size_t)(f >> 5) * YHALF + (size_t)n * 32 + (f & 31)] = __float2bfloat16(d * v);
    }
}

// ---------- projection GEMM: 128x64 tile per block, K-tile 32; w transposed in LDS ----------
__global__ __launch_bounds__(256) void k_proj(const float* __restrict__ bert,
                                              const float* __restrict__ w,
                                              const float* __restrict__ dis,
                                              float* __restrict__ out,
                                              bf16* __restrict__ y) {
    __shared__ float sB[128][33];
    __shared__ float sW[32][64];
    const int tid  = threadIdx.x;
    const int rb   = blockIdx.x * 128;
    const int col8 = (tid & 7) * 8;
    const int rowg = (tid >> 3) * 4;

    float acc[4][8];
#pragma unroll
    for (int i = 0; i < 4; ++i)
#pragma unroll
        for (int j = 0; j < 8; ++j) acc[i][j] = 0.0f;

    for (int kb = 0; kb < SBERT; kb += 32) {
        __syncthreads();
#pragma unroll
        for (int j = 0; j < 4; ++j) {
            int idx = tid + j * 256;
            int r  = idx >> 3;
            int k4 = (idx & 7) * 4;
            int rr = min(rb + r, NUM_ITEMS - 1);
            float4 v = *(const float4*)(bert + (size_t)rr * SBERT + kb + k4);
            sB[r][k4 + 0] = v.x; sB[r][k4 + 1] = v.y;
            sB[r][k4 + 2] = v.z; sB[r][k4 + 3] = v.w;
        }
#pragma unroll
        for (int j = 0; j < 2; ++j) {
            int idx = tid + j * 256;
            int c  = idx >> 3;
            int k4 = (idx & 7) * 4;
            float4 v = *(const float4*)(w + (size_t)c * SBERT + kb + k4);
            sW[k4 + 0][c] = v.x; sW[k4 + 1][c] = v.y;
            sW[k4 + 2][c] = v.z; sW[k4 + 3][c] = v.w;
        }
        __syncthreads();
#pragma unroll
        for (int kk = 0; kk < 32; ++kk) {
            float4 w0 = *(const float4*)&sW[kk][col8];
            float4 w1 = *(const float4*)&sW[kk][col8 + 4];
#pragma unroll
            for (int i = 0; i < 4; ++i) {
                float a = sB[rowg + i][kk];
                acc[i][0] = fmaf(a, w0.x, acc[i][0]);
                acc[i][1] = fmaf(a, w0.y, acc[i][1]);
                acc[i][2] = fmaf(a, w0.z, acc[i][2]);
                acc[i][3] = fmaf(a, w0.w, acc[i][3]);
                acc[i][4] = fmaf(a, w1.x, acc[i][4]);
                acc[i][5] = fmaf(a, w1.y, acc[i][5]);
                acc[i][6] = fmaf(a, w1.z, acc[i][6]);
                acc[i][7] = fmaf(a, w1.w, acc[i][7]);
            }
        }
    }
#pragma unroll
    for (int i = 0; i < 4; ++i) {
        int r = rb + rowg + i;
        if (r < NUM_ITEMS) {
            int n = NUM_USERS + r;
            size_t o = (size_t)n * LATENT + col8;
            float d = dis[n];
            float4 f0 = make_float4(acc[i][0], acc[i][1], acc[i][2], acc[i][3]);
            float4 f1 = make_float4(acc[i][4], acc[i][5], acc[i][6], acc[i][7]);
            *(float4*)(out + o)           = f0;
            *(float4*)(out + o + 4)       = f1;
            *(float4*)(out + OUT_OFF + o) = f0;
            *(float4*)(out + OUT_OFF + o + 4) = f1;
            // y layout: [half][node][32]; col8..col8+7 stays within one half
            size_t yo = (size_t)(col8 >> 5) * YHALF + (size_t)n * 32 + (col8 & 31);
#pragma unroll
            for (int j = 0; j < 8; ++j) y[yo + j] = __float2bfloat16(d * acc[i][j]);
        }
    }
}

// ---------- SpMM over one 32-feature half; wave per dst node; paired-edge gathers ----------
// lanes 0-31: even edge, feat=lane; lanes 32-63: odd edge, feat=lane-32.
// Each 8-load batch covers 16 edges (64B/edge = full cache line, zero waste).
// S = sum yh[src][feat]; acc[:,FOFF half] += dis*S; yn_half = bf16(dis^2 * S)
template <bool FINAL>
__global__ __launch_bounds__(256) void k_spmm(const bf16* __restrict__ yh,   // [N][32] this half
                                              const int* __restrict__ rp,
                                              const int* __restrict__ cws,
                                              const float* __restrict__ dis,
                                              bf16* __restrict__ ynh,        // [N][32] this half
                                              float* __restrict__ acch) {    // acc + FOFF
    int lane = threadIdx.x & 63;
    int par  = lane >> 5;                                   // edge parity
    int feat = lane & 31;
    int node = ufl(blockIdx.x * 4 + (threadIdx.x >> 6));    // 37500*4 = 150000 exact
    int beg = rp[node];
    int end = rp[node + 1];
    int last = end - 1;
    float d = dis[node];                                    // hoisted (wave-uniform)
    size_t o = (size_t)node * LATENT + feat;
    float accv = acch[o];                                   // prefetch (dup addrs in hi half)
    float a = 0.0f;
    for (int base = beg; base < end; base += 16) {
        int idx[8];
#pragma unroll
        for (int j = 0; j < 8; ++j)
            idx[j] = cws[min(base + 2 * j + par, last)];
        float v[8];
#pragma unroll
        for (int j = 0; j < 8; ++j)
            v[j] = __bfloat162float(yh[(size_t)idx[j] * 32 + feat]);
#pragma unroll
        for (int j = 0; j < 8; ++j)
            if (base + 2 * j + par <= last) a += v[j];
    }
    a += __shfl_xor(a, 32);                                 // merge even/odd partials
    if (lane < 32) {
        float t = accv + d * a;
        acch[o] = FINAL ? t * 0.25f : t;
    } else if (!FINAL) {
        ynh[(size_t)node * 32 + feat] = __float2bfloat16(d * d * a);
    }
}

extern "C" void kernel_launch(void* const* d_in, const int* in_sizes, int n_in,
                              void* d_out, int out_size, void* d_ws, size_t ws_size,
                              hipStream_t stream) {
    const int*   ei    = (const int*)d_in[0];
    const float* uemb  = (const float*)d_in[1];
    const float* bert  = (const float*)d_in[2];
    const float* wproj = (const float*)d_in[3];
    float* out = (float*)d_out;

    char* ws = (char*)d_ws;
    size_t off = 0;
    auto carve = [&](size_t bytes) -> void* {
        void* p = ws + off;
        off += (bytes + 255) & ~(size_t)255;
        return p;
    };
    float*    dis    = (float*)carve(sizeof(float) * N_NODES);
    int*      rp     = (int*)carve(sizeof(int) * (N_NODES + 1));
    int*      bcnt   = (int*)carve(sizeof(int) * NBUCK);
    int*      bbase  = (int*)carve(sizeof(int) * (NBUCK + 1));
    unsigned* bin    = (unsigned*)carve(sizeof(unsigned) * (size_t)NBUCK * BCAP);
    int*      cws    = (int*)carve(sizeof(int) * N_EDGES);
    bf16*     ye     = (bf16*)carve(sizeof(bf16) * (size_t)N_NODES * LATENT);
    bf16*     y0     = (bf16*)carve(sizeof(bf16) * (size_t)N_NODES * LATENT);
    bf16*     y1     = (bf16*)carve(sizeof(bf16) * (size_t)N_NODES * LATENT);

    const int* srcI = ei;
    const int* dstI = ei + N_EDGES;

    k_zero_bcnt<<<(NBUCK + 255) / 256, 256, 0, stream>>>(bcnt);
    k_bin<<<(N_EDGES + EPB - 1) / EPB, 256, 0, stream>>>(srcI, dstI, bcnt, bin);
    k_bscan<<<1, 1024, 0, stream>>>(bcnt, bbase);
    k_build<<<NBUCK, 256, 0, stream>>>(bin, bcnt, bbase, rp, dis, cws);
    k_copy_user<<<(NUM_USERS * LATENT + 255) / 256, 256, 0, stream>>>(uemb, dis, out, ye);
    k_proj<<<(NUM_ITEMS + 127) / 128, 256, 0, stream>>>(bert, wproj, dis, out, ye);

    float* accp = out + OUT_OFF;
    const int G = N_NODES / 4;
    // layer 1
    k_spmm<false><<<G, 256, 0, stream>>>(ye,         rp, cws, dis, y0,         accp);
    k_spmm<false><<<G, 256, 0, stream>>>(ye + YHALF, rp, cws, dis, y0 + YHALF, accp + 32);
    // layer 2
    k_spmm<false><<<G, 256, 0, stream>>>(y0,         rp, cws, dis, y1,         accp);
    k_spmm<false><<<G, 256, 0, stream>>>(y0 + YHALF, rp, cws, dis, y1 + YHALF, accp + 32);
    // layer 3 + /4
    k_spmm<true ><<<G, 256, 0, stream>>>(y1,         rp, cws, dis, y0,         accp);
    k_spmm<true ><<<G, 256, 0, stream>>>(y1 + YHALF, rp, cws, dis, y0 + YHALF, accp + 32);
}

// Round 3
// 454.636 us; speedup vs baseline: 1.2266x; 1.2266x over previous
//
#include <hip/hip_runtime.h>
#include <hip/hip_bf16.h>
#include <stdint.h>

#define NUM_USERS 100000
#define NUM_ITEMS 50000
#define N_NODES   150000
#define LATENT    64
#define SBERT     384
#define N_EDGES   2000000
#define OUT_OFF   (N_NODES * LATENT)   // out = d_out + OUT_OFF
#define NBUCK     586                  // ceil(150000 / 256), 256 nodes per bucket
#define BCAP      4096                 // fixed bin capacity per bucket (mean 3413, sigma 58)
#define EPB       4096                 // edges per k_bin block (489 blocks, 16 edges/thread)

typedef __hip_bfloat16 bf16;

__device__ __forceinline__ int ufl(int v) { return __builtin_amdgcn_readfirstlane(v); }

__device__ __forceinline__ void nt_store_bf16(bf16* p, bf16 v) {
    __builtin_nontemporal_store(*reinterpret_cast<unsigned short*>(&v),
                                reinterpret_cast<unsigned short*>(p));
}

// ---------- zero bucket counters ----------
__global__ void k_zero_bcnt(int* __restrict__ bcnt) {
    int i = blockIdx.x * 256 + threadIdx.x;
    if (i < NBUCK) bcnt[i] = 0;
}

// ---------- binning: bucket edges by dst>>8 into fixed-capacity bins ----------
// Single global read pass: 16 edges/thread staged in VGPRs, reused across both
// LDS-atomic phases. All 16 atomics are independent -> pipelined, not chained.
__global__ __launch_bounds__(256) void k_bin(const int* __restrict__ src,
                                             const int* __restrict__ dst,
                                             int* __restrict__ bcnt,
                                             unsigned* __restrict__ bin) {
    __shared__ int hist[NBUCK];
    __shared__ int base[NBUCK];
    const int tid = threadIdx.x;
    for (int i = tid; i < NBUCK; i += 256) hist[i] = 0;
    const int e0 = blockIdx.x * EPB;

    unsigned rec[16];
    int bb[16];
#pragma unroll
    for (int j = 0; j < 16; ++j) {
        int e = e0 + tid + j * 256;
        if (e < N_EDGES) {
            int d = __builtin_nontemporal_load(dst + e);
            int s = __builtin_nontemporal_load(src + e);
            bb[j]  = d >> 8;
            rec[j] = (unsigned)s | ((unsigned)(d & 255) << 18);  // src < 2^18
        } else {
            bb[j] = -1;
        }
    }
    __syncthreads();
#pragma unroll
    for (int j = 0; j < 16; ++j)
        if (bb[j] >= 0) atomicAdd(&hist[bb[j]], 1);   // no return -> fire-and-forget
    __syncthreads();
    for (int i = tid; i < NBUCK; i += 256) {
        int c = hist[i];
        base[i] = c ? atomicAdd(&bcnt[i], c) : 0;
        hist[i] = 0;                       // reuse as local cursor
    }
    __syncthreads();
    int p[16];
#pragma unroll
    for (int j = 0; j < 16; ++j)
        if (bb[j] >= 0) p[j] = atomicAdd(&hist[bb[j]], 1);   // 16 independent rtn-atomics
#pragma unroll
    for (int j = 0; j < 16; ++j)
        if (bb[j] >= 0)
            bin[(size_t)bb[j] * BCAP + base[bb[j]] + p[j]] = rec[j];
}

// ---------- exclusive scan of 586 bucket counts (single block) ----------
__global__ __launch_bounds__(1024) void k_bscan(const int* __restrict__ bcnt,
                                                int* __restrict__ bbase) {
    __shared__ int sm[1024];
    int tid = threadIdx.x;
    int v = (tid < NBUCK) ? bcnt[tid] : 0;
    sm[tid] = v;
    __syncthreads();
    for (int off = 1; off < 1024; off <<= 1) {
        int t = (tid >= off) ? sm[tid - off] : 0;
        __syncthreads();
        sm[tid] += t;
        __syncthreads();
    }
    if (tid <= NBUCK) bbase[tid] = (tid == 0) ? 0 : sm[tid - 1];
}

// ---------- per-bucket: degree histogram -> rp, dis; scatter src-only CSR ----------
__global__ __launch_bounds__(256) void k_build(const unsigned* __restrict__ bin,
                                               const int* __restrict__ bcnt,
                                               const int* __restrict__ bbase,
                                               int* __restrict__ rp,
                                               float* __restrict__ dis,
                                               int* __restrict__ cws) {
    __shared__ int h[256];
    __shared__ int lc[256];
    const int tid   = threadIdx.x;
    const int b     = blockIdx.x;
    const int nbase = b << 8;
    const unsigned* mybin = bin + (size_t)b * BCAP;
    h[tid] = 0;
    __syncthreads();
    const int cnt  = bcnt[b];
    const int base = bbase[b];
    for (int i = tid; i < cnt; i += 256)
        atomicAdd(&h[__builtin_nontemporal_load(mybin + i) >> 18], 1);
    __syncthreads();
    int v = h[tid];
    // block exclusive scan of h
    __shared__ int sm[256];
    sm[tid] = v;
    __syncthreads();
    for (int off = 1; off < 256; off <<= 1) {
        int t = (tid >= off) ? sm[tid - off] : 0;
        __syncthreads();
        sm[tid] += t;
        __syncthreads();
    }
    int excl = sm[tid] - v;
    int n = nbase + tid;
    if (n < N_NODES) {
        rp[n]  = base + excl;
        dis[n] = (v > 0) ? rsqrtf((float)v) : 0.0f;
    }
    lc[tid] = base + excl;
    if (b == NBUCK - 1 && tid == 0) rp[N_NODES] = N_EDGES;
    __syncthreads();
    for (int i = tid; i < cnt; i += 256) {
        unsigned rec = __builtin_nontemporal_load(mybin + i);
        int dl = rec >> 18;
        int pos = atomicAdd(&lc[dl], 1);
        cws[pos] = (int)(rec & 0x3FFFF);
    }
}

// ---------- copy user_emb into emb0 + acc (fp32) and y0 = bf16(dis*u) ----------
__global__ void k_copy_user(const float* __restrict__ u, const float* __restrict__ dis,
                            float* __restrict__ out, bf16* __restrict__ y) {
    int i = blockIdx.x * 256 + threadIdx.x;
    if (i < NUM_USERS * LATENT) {
        float v = __builtin_nontemporal_load(u + i);
        __builtin_nontemporal_store(v, out + i);             // emb0
        __builtin_nontemporal_store(v, out + OUT_OFF + i);   // acc init
        float d = dis[i >> 6];           // wave-uniform
        y[i] = __float2bfloat16(d * v);  // layer-1 gather input (pre-scaled)
    }
}

// ---------- projection GEMM: 128x64 tile per block, K-tile 32; w transposed in LDS ----------
__global__ __launch_bounds__(256) void k_proj(const float* __restrict__ bert,
                                              const float* __restrict__ w,
                                              const float* __restrict__ dis,
                                              float* __restrict__ out,
                                              bf16* __restrict__ y) {
    __shared__ float sB[128][33];
    __shared__ float sW[32][64];
    const int tid  = threadIdx.x;
    const int rb   = blockIdx.x * 128;
    const int col8 = (tid & 7) * 8;
    const int rowg = (tid >> 3) * 4;

    float acc[4][8];
#pragma unroll
    for (int i = 0; i < 4; ++i)
#pragma unroll
        for (int j = 0; j < 8; ++j) acc[i][j] = 0.0f;

    for (int kb = 0; kb < SBERT; kb += 32) {
        __syncthreads();
#pragma unroll
        for (int j = 0; j < 4; ++j) {
            int idx = tid + j * 256;
            int r  = idx >> 3;
            int k4 = (idx & 7) * 4;
            int rr = min(rb + r, NUM_ITEMS - 1);
            const float* bp = bert + (size_t)rr * SBERT + kb + k4;
            float4 v = make_float4(__builtin_nontemporal_load(bp + 0),
                                   __builtin_nontemporal_load(bp + 1),
                                   __builtin_nontemporal_load(bp + 2),
                                   __builtin_nontemporal_load(bp + 3));
            sB[r][k4 + 0] = v.x; sB[r][k4 + 1] = v.y;
            sB[r][k4 + 2] = v.z; sB[r][k4 + 3] = v.w;
        }
#pragma unroll
        for (int j = 0; j < 2; ++j) {
            int idx = tid + j * 256;
            int c  = idx >> 3;
            int k4 = (idx & 7) * 4;
            float4 v = *(const float4*)(w + (size_t)c * SBERT + kb + k4);
            sW[k4 + 0][c] = v.x; sW[k4 + 1][c] = v.y;
            sW[k4 + 2][c] = v.z; sW[k4 + 3][c] = v.w;
        }
        __syncthreads();
#pragma unroll
        for (int kk = 0; kk < 32; ++kk) {
            float4 w0 = *(const float4*)&sW[kk][col8];
            float4 w1 = *(const float4*)&sW[kk][col8 + 4];
#pragma unroll
            for (int i = 0; i < 4; ++i) {
                float a = sB[rowg + i][kk];
                acc[i][0] = fmaf(a, w0.x, acc[i][0]);
                acc[i][1] = fmaf(a, w0.y, acc[i][1]);
                acc[i][2] = fmaf(a, w0.z, acc[i][2]);
                acc[i][3] = fmaf(a, w0.w, acc[i][3]);
                acc[i][4] = fmaf(a, w1.x, acc[i][4]);
                acc[i][5] = fmaf(a, w1.y, acc[i][5]);
                acc[i][6] = fmaf(a, w1.z, acc[i][6]);
                acc[i][7] = fmaf(a, w1.w, acc[i][7]);
            }
        }
    }
#pragma unroll
    for (int i = 0; i < 4; ++i) {
        int r = rb + rowg + i;
        if (r < NUM_ITEMS) {
            int n = NUM_USERS + r;
            size_t o = (size_t)n * LATENT + col8;
            float d = dis[n];
#pragma unroll
            for (int j = 0; j < 8; ++j) {
                __builtin_nontemporal_store(acc[i][j], out + o + j);
                __builtin_nontemporal_store(acc[i][j], out + OUT_OFF + o + j);
                y[o + j] = __float2bfloat16(d * acc[i][j]);
            }
        }
    }
}

// ---------- SpMM: wave per dst node; src-only CSR; 8-deep predicated gather ----------
// S = sum y[src]; acc += dis[d]*S; y_next = bf16(dis[d]^2 * S)
// acc/y_next stores are non-temporal: 57.6 MB/layer of write traffic that is
// never re-read before eviction -> keep it out of the L2 the gathers need.
template <bool FINAL>
__global__ __launch_bounds__(256) void k_spmm(const bf16* __restrict__ y,
                                              const int* __restrict__ rp,
                                              const int* __restrict__ cws,
                                              const float* __restrict__ dis,
                                              bf16* __restrict__ yn,
                                              float* __restrict__ acc) {
    int lane = threadIdx.x & 63;
    int node = ufl(blockIdx.x * 4 + (threadIdx.x >> 6));   // 37500*4 = 150000 exact
    int beg = rp[node];
    int end = rp[node + 1];
    int last = end - 1;
    float d = dis[node];                                   // hoisted, wave-uniform
    size_t o = (size_t)node * LATENT + lane;
    float accv = acc[o];                                   // prefetch before gather loop
    float a = 0.0f;
    for (int base = beg; base < end; base += 8) {
        int idx[8];
#pragma unroll
        for (int j = 0; j < 8; ++j)
            idx[j] = cws[min(base + j, last)];
        float v[8];
#pragma unroll
        for (int j = 0; j < 8; ++j)
            v[j] = __bfloat162float(y[(size_t)idx[j] * LATENT + lane]);
#pragma unroll
        for (int j = 0; j < 8; ++j)
            if (base + j <= last) a += v[j];     // wave-uniform predicate
    }
    if (!FINAL)
        nt_store_bf16(yn + o, __float2bfloat16(d * d * a));
    float t = accv + d * a;
    __builtin_nontemporal_store(FINAL ? t * 0.25f : t, acc + o);
}

extern "C" void kernel_launch(void* const* d_in, const int* in_sizes, int n_in,
                              void* d_out, int out_size, void* d_ws, size_t ws_size,
                              hipStream_t stream) {
    const int*   ei    = (const int*)d_in[0];
    const float* uemb  = (const float*)d_in[1];
    const float* bert  = (const float*)d_in[2];
    const float* wproj = (const float*)d_in[3];
    float* out = (float*)d_out;

    char* ws = (char*)d_ws;
    size_t off = 0;
    auto carve = [&](size_t bytes) -> void* {
        void* p = ws + off;
        off += (bytes + 255) & ~(size_t)255;
        return p;
    };
    float*    dis    = (float*)carve(sizeof(float) * N_NODES);
    int*      rp     = (int*)carve(sizeof(int) * (N_NODES + 1));
    int*      bcnt   = (int*)carve(sizeof(int) * NBUCK);
    int*      bbase  = (int*)carve(sizeof(int) * (NBUCK + 1));
    unsigned* bin    = (unsigned*)carve(sizeof(unsigned) * (size_t)NBUCK * BCAP);
    int*      cws    = (int*)carve(sizeof(int) * N_EDGES);
    bf16*     ye     = (bf16*)carve(sizeof(bf16) * (size_t)N_NODES * LATENT);
    bf16*     y0     = (bf16*)carve(sizeof(bf16) * (size_t)N_NODES * LATENT);
    bf16*     y1     = (bf16*)carve(sizeof(bf16) * (size_t)N_NODES * LATENT);

    const int* srcI = ei;
    const int* dstI = ei + N_EDGES;

    k_zero_bcnt<<<(NBUCK + 255) / 256, 256, 0, stream>>>(bcnt);
    k_bin<<<(N_EDGES + EPB - 1) / EPB, 256, 0, stream>>>(srcI, dstI, bcnt, bin);
    k_bscan<<<1, 1024, 0, stream>>>(bcnt, bbase);
    k_build<<<NBUCK, 256, 0, stream>>>(bin, bcnt, bbase, rp, dis, cws);
    k_copy_user<<<(NUM_USERS * LATENT + 255) / 256, 256, 0, stream>>>(uemb, dis, out, ye);
    k_proj<<<(NUM_ITEMS + 127) / 128, 256, 0, stream>>>(bert, wproj, dis, out, ye);

    float* accp = out + OUT_OFF;
    k_spmm<false><<<N_NODES / 4, 256, 0, stream>>>(ye, rp, cws, dis, y0, accp);  // layer 1
    k_spmm<false><<<N_NODES / 4, 256, 0, stream>>>(y0, rp, cws, dis, y1, accp);  // layer 2
    k_spmm<true ><<<N_NODES / 4, 256, 0, stream>>>(y1, rp, cws, dis, y0, accp);  // layer 3 + /4
}

// Round 4
// 447.656 us; speedup vs baseline: 1.2457x; 1.0156x over previous
//
#include <hip/hip_runtime.h>
#include <hip/hip_bf16.h>
#include <stdint.h>

#define NUM_USERS 100000
#define NUM_ITEMS 50000
#define N_NODES   150000
#define LATENT    64
#define SBERT     384
#define N_EDGES   2000000
#define OUT_OFF   (N_NODES * LATENT)   // out = d_out + OUT_OFF
#define NBUCK     586                  // ceil(150000 / 256), 256 nodes per bucket
#define BCAP      4096                 // fixed bin capacity per bucket (mean 3413, sigma 58)
#define EPB       4096                 // edges per k_bin block (489 blocks, 16 edges/thread)

typedef __hip_bfloat16 bf16;

__device__ __forceinline__ int ufl(int v) { return __builtin_amdgcn_readfirstlane(v); }

// ---------- zero bucket counters ----------
__global__ void k_zero_bcnt(int* __restrict__ bcnt) {
    int i = blockIdx.x * 256 + threadIdx.x;
    if (i < NBUCK) bcnt[i] = 0;
}

// ---------- binning: bucket edges by dst>>8 into fixed-capacity bins ----------
// Single global read pass: 16 edges/thread staged in VGPRs, reused across both
// LDS-atomic phases. All 16 atomics are independent -> pipelined, not chained.
__global__ __launch_bounds__(256) void k_bin(const int* __restrict__ src,
                                             const int* __restrict__ dst,
                                             int* __restrict__ bcnt,
                                             unsigned* __restrict__ bin) {
    __shared__ int hist[NBUCK];
    __shared__ int base[NBUCK];
    const int tid = threadIdx.x;
    for (int i = tid; i < NBUCK; i += 256) hist[i] = 0;
    const int e0 = blockIdx.x * EPB;

    unsigned rec[16];
    int bb[16];
#pragma unroll
    for (int j = 0; j < 16; ++j) {
        int e = e0 + tid + j * 256;
        if (e < N_EDGES) {
            int d = __builtin_nontemporal_load(dst + e);
            int s = __builtin_nontemporal_load(src + e);
            bb[j]  = d >> 8;
            rec[j] = (unsigned)s | ((unsigned)(d & 255) << 18);  // src < 2^18
        } else {
            bb[j] = -1;
        }
    }
    __syncthreads();
#pragma unroll
    for (int j = 0; j < 16; ++j)
        if (bb[j] >= 0) atomicAdd(&hist[bb[j]], 1);   // no return -> fire-and-forget
    __syncthreads();
    for (int i = tid; i < NBUCK; i += 256) {
        int c = hist[i];
        base[i] = c ? atomicAdd(&bcnt[i], c) : 0;
        hist[i] = 0;                       // reuse as local cursor
    }
    __syncthreads();
    int p[16];
#pragma unroll
    for (int j = 0; j < 16; ++j)
        if (bb[j] >= 0) p[j] = atomicAdd(&hist[bb[j]], 1);   // 16 independent rtn-atomics
#pragma unroll
    for (int j = 0; j < 16; ++j)
        if (bb[j] >= 0)
            bin[(size_t)bb[j] * BCAP + base[bb[j]] + p[j]] = rec[j];
}

// ---------- exclusive scan of 586 bucket counts (single block) ----------
__global__ __launch_bounds__(1024) void k_bscan(const int* __restrict__ bcnt,
                                                int* __restrict__ bbase) {
    __shared__ int sm[1024];
    int tid = threadIdx.x;
    int v = (tid < NBUCK) ? bcnt[tid] : 0;
    sm[tid] = v;
    __syncthreads();
    for (int off = 1; off < 1024; off <<= 1) {
        int t = (tid >= off) ? sm[tid - off] : 0;
        __syncthreads();
        sm[tid] += t;
        __syncthreads();
    }
    if (tid <= NBUCK) bbase[tid] = (tid == 0) ? 0 : sm[tid - 1];
}

// ---------- per-bucket: degree histogram -> rp, dis; scatter src-only CSR ----------
__global__ __launch_bounds__(256) void k_build(const unsigned* __restrict__ bin,
                                               const int* __restrict__ bcnt,
                                               const int* __restrict__ bbase,
                                               int* __restrict__ rp,
                                               float* __restrict__ dis,
                                               int* __restrict__ cws) {
    __shared__ int h[256];
    __shared__ int lc[256];
    const int tid   = threadIdx.x;
    const int b     = blockIdx.x;
    const int nbase = b << 8;
    const unsigned* mybin = bin + (size_t)b * BCAP;
    h[tid] = 0;
    __syncthreads();
    const int cnt  = bcnt[b];
    const int base = bbase[b];
    for (int i = tid; i < cnt; i += 256)
        atomicAdd(&h[__builtin_nontemporal_load(mybin + i) >> 18], 1);
    __syncthreads();
    int v = h[tid];
    // block exclusive scan of h
    __shared__ int sm[256];
    sm[tid] = v;
    __syncthreads();
    for (int off = 1; off < 256; off <<= 1) {
        int t = (tid >= off) ? sm[tid - off] : 0;
        __syncthreads();
        sm[tid] += t;
        __syncthreads();
    }
    int excl = sm[tid] - v;
    int n = nbase + tid;
    if (n < N_NODES) {
        rp[n]  = base + excl;
        dis[n] = (v > 0) ? rsqrtf((float)v) : 0.0f;
    }
    lc[tid] = base + excl;
    if (b == NBUCK - 1 && tid == 0) rp[N_NODES] = N_EDGES;
    __syncthreads();
    for (int i = tid; i < cnt; i += 256) {
        unsigned rec = __builtin_nontemporal_load(mybin + i);
        int dl = rec >> 18;
        int pos = atomicAdd(&lc[dl], 1);
        cws[pos] = (int)(rec & 0x3FFFF);
    }
}

// ---------- copy user_emb into emb0 + acc (fp32) and y0 = bf16(dis*u) ----------
__global__ void k_copy_user(const float* __restrict__ u, const float* __restrict__ dis,
                            float* __restrict__ out, bf16* __restrict__ y) {
    int i = blockIdx.x * 256 + threadIdx.x;
    if (i < NUM_USERS * LATENT) {
        float v = __builtin_nontemporal_load(u + i);
        out[i] = v;                      // emb0
        out[OUT_OFF + i] = v;            // acc init
        float d = dis[i >> 6];           // wave-uniform
        y[i] = __float2bfloat16(d * v);  // layer-1 gather input (pre-scaled)
    }
}

// ---------- projection GEMM: 128x64 tile per block, K-tile 32; w transposed in LDS ----------
__global__ __launch_bounds__(256) void k_proj(const float* __restrict__ bert,
                                              const float* __restrict__ w,
                                              const float* __restrict__ dis,
                                              float* __restrict__ out,
                                              bf16* __restrict__ y) {
    __shared__ float sB[128][33];
    __shared__ float sW[32][64];
    const int tid  = threadIdx.x;
    const int rb   = blockIdx.x * 128;
    const int col8 = (tid & 7) * 8;
    const int rowg = (tid >> 3) * 4;

    float acc[4][8];
#pragma unroll
    for (int i = 0; i < 4; ++i)
#pragma unroll
        for (int j = 0; j < 8; ++j) acc[i][j] = 0.0f;

    for (int kb = 0; kb < SBERT; kb += 32) {
        __syncthreads();
#pragma unroll
        for (int j = 0; j < 4; ++j) {
            int idx = tid + j * 256;
            int r  = idx >> 3;
            int k4 = (idx & 7) * 4;
            int rr = min(rb + r, NUM_ITEMS - 1);
            const float* bp = bert + (size_t)rr * SBERT + kb + k4;
            float4 v = make_float4(__builtin_nontemporal_load(bp + 0),
                                   __builtin_nontemporal_load(bp + 1),
                                   __builtin_nontemporal_load(bp + 2),
                                   __builtin_nontemporal_load(bp + 3));
            sB[r][k4 + 0] = v.x; sB[r][k4 + 1] = v.y;
            sB[r][k4 + 2] = v.z; sB[r][k4 + 3] = v.w;
        }
#pragma unroll
        for (int j = 0; j < 2; ++j) {
            int idx = tid + j * 256;
            int c  = idx >> 3;
            int k4 = (idx & 7) * 4;
            float4 v = *(const float4*)(w + (size_t)c * SBERT + kb + k4);
            sW[k4 + 0][c] = v.x; sW[k4 + 1][c] = v.y;
            sW[k4 + 2][c] = v.z; sW[k4 + 3][c] = v.w;
        }
        __syncthreads();
#pragma unroll
        for (int kk = 0; kk < 32; ++kk) {
            float4 w0 = *(const float4*)&sW[kk][col8];
            float4 w1 = *(const float4*)&sW[kk][col8 + 4];
#pragma unroll
            for (int i = 0; i < 4; ++i) {
                float a = sB[rowg + i][kk];
                acc[i][0] = fmaf(a, w0.x, acc[i][0]);
                acc[i][1] = fmaf(a, w0.y, acc[i][1]);
                acc[i][2] = fmaf(a, w0.z, acc[i][2]);
                acc[i][3] = fmaf(a, w0.w, acc[i][3]);
                acc[i][4] = fmaf(a, w1.x, acc[i][4]);
                acc[i][5] = fmaf(a, w1.y, acc[i][5]);
                acc[i][6] = fmaf(a, w1.z, acc[i][6]);
                acc[i][7] = fmaf(a, w1.w, acc[i][7]);
            }
        }
    }
#pragma unroll
    for (int i = 0; i < 4; ++i) {
        int r = rb + rowg + i;
        if (r < NUM_ITEMS) {
            int n = NUM_USERS + r;
            size_t o = (size_t)n * LATENT + col8;
            float d = dis[n];
            float4 f0 = make_float4(acc[i][0], acc[i][1], acc[i][2], acc[i][3]);
            float4 f1 = make_float4(acc[i][4], acc[i][5], acc[i][6], acc[i][7]);
            *(float4*)(out + o)           = f0;
            *(float4*)(out + o + 4)       = f1;
            *(float4*)(out + OUT_OFF + o) = f0;
            *(float4*)(out + OUT_OFF + o + 4) = f1;
#pragma unroll
            for (int j = 0; j < 8; ++j) y[o + j] = __float2bfloat16(d * acc[i][j]);
        }
    }
}

// ---------- SpMM: wave per dst node; src-only CSR; 16-deep predicated gather ----------
// Mean degree 13.3 -> 81% of waves complete in ONE idx->gather latency round
// (vs two at 8-deep). Clamped duplicate gathers hit the same line in L1 (cheap).
// S = sum y[src]; acc += dis[d]*S; y_next = bf16(dis[d]^2 * S)
template <bool FINAL>
__global__ __launch_bounds__(256) void k_spmm(const bf16* __restrict__ y,
                                              const int* __restrict__ rp,
                                              const int* __restrict__ cws,
                                              const float* __restrict__ dis,
                                              bf16* __restrict__ yn,
                                              float* __restrict__ acc) {
    int lane = threadIdx.x & 63;
    int node = ufl(blockIdx.x * 4 + (threadIdx.x >> 6));   // 37500*4 = 150000 exact
    int beg = rp[node];
    int end = rp[node + 1];
    int last = end - 1;
    float d = dis[node];                                   // hoisted, wave-uniform
    size_t o = (size_t)node * LATENT + lane;
    float accv = acc[o];                                   // prefetch before gather loop
    float a = 0.0f;
    for (int base = beg; base < end; base += 16) {
        int idx[16];
#pragma unroll
        for (int j = 0; j < 16; ++j)
            idx[j] = cws[min(base + j, last)];
        float v[16];
#pragma unroll
        for (int j = 0; j < 16; ++j)
            v[j] = __bfloat162float(y[(size_t)idx[j] * LATENT + lane]);
#pragma unroll
        for (int j = 0; j < 16; ++j)
            if (base + j <= last) a += v[j];     // wave-uniform predicate
    }
    if (!FINAL) yn[o] = __float2bfloat16(d * d * a);
    float t = accv + d * a;
    acc[o] = FINAL ? t * 0.25f : t;
}

extern "C" void kernel_launch(void* const* d_in, const int* in_sizes, int n_in,
                              void* d_out, int out_size, void* d_ws, size_t ws_size,
                              hipStream_t stream) {
    const int*   ei    = (const int*)d_in[0];
    const float* uemb  = (const float*)d_in[1];
    const float* bert  = (const float*)d_in[2];
    const float* wproj = (const float*)d_in[3];
    float* out = (float*)d_out;

    char* ws = (char*)d_ws;
    size_t off = 0;
    auto carve = [&](size_t bytes) -> void* {
        void* p = ws + off;
        off += (bytes + 255) & ~(size_t)255;
        return p;
    };
    float*    dis    = (float*)carve(sizeof(float) * N_NODES);
    int*      rp     = (int*)carve(sizeof(int) * (N_NODES + 1));
    int*      bcnt   = (int*)carve(sizeof(int) * NBUCK);
    int*      bbase  = (int*)carve(sizeof(int) * (NBUCK + 1));
    unsigned* bin    = (unsigned*)carve(sizeof(unsigned) * (size_t)NBUCK * BCAP);
    int*      cws    = (int*)carve(sizeof(int) * N_EDGES);
    bf16*     ye     = (bf16*)carve(sizeof(bf16) * (size_t)N_NODES * LATENT);
    bf16*     y0     = (bf16*)carve(sizeof(bf16) * (size_t)N_NODES * LATENT);
    bf16*     y1     = (bf16*)carve(sizeof(bf16) * (size_t)N_NODES * LATENT);

    const int* srcI = ei;
    const int* dstI = ei + N_EDGES;

    k_zero_bcnt<<<(NBUCK + 255) / 256, 256, 0, stream>>>(bcnt);
    k_bin<<<(N_EDGES + EPB - 1) / EPB, 256, 0, stream>>>(srcI, dstI, bcnt, bin);
    k_bscan<<<1, 1024, 0, stream>>>(bcnt, bbase);
    k_build<<<NBUCK, 256, 0, stream>>>(bin, bcnt, bbase, rp, dis, cws);
    k_copy_user<<<(NUM_USERS * LATENT + 255) / 256, 256, 0, stream>>>(uemb, dis, out, ye);
    k_proj<<<(NUM_ITEMS + 127) / 128, 256, 0, stream>>>(bert, wproj, dis, out, ye);

    float* accp = out + OUT_OFF;
    k_spmm<false><<<N_NODES / 4, 256, 0, stream>>>(ye, rp, cws, dis, y0, accp);  // layer 1
    k_spmm<false><<<N_NODES / 4, 256, 0, stream>>>(y0, rp, cws, dis, y1, accp);  // layer 2
    k_spmm<true ><<<N_NODES / 4, 256, 0, stream>>>(y1, rp, cws, dis, y0, accp);  // layer 3 + /4
}

// Round 5
// 440.251 us; speedup vs baseline: 1.2667x; 1.0168x over previous
//
#include <hip/hip_runtime.h>
#include <hip/hip_bf16.h>
#include <hip/hip_cooperative_groups.h>
#include <stdint.h>

namespace cg = cooperative_groups;

#define NUM_USERS 100000
#define NUM_ITEMS 50000
#define N_NODES   150000
#define LATENT    64
#define SBERT     384
#define N_EDGES   2000000
#define OUT_OFF   (N_NODES * LATENT)   // out = d_out + OUT_OFF
#define NBUCK     586                  // ceil(150000 / 256), 256 nodes per bucket
#define BCAP      4096                 // fixed bin capacity per bucket (mean 3413, sigma 58)
#define EPB       4096                 // edges per k_bin block (489 blocks, 16 edges/thread)
#define PBLK      1024                 // persistent grid: 1024 blocks * 4 waves = 4096 waves
#define PWAVES    4096
#define NPW       37                   // ceil(150000 / 4096) nodes per wave

typedef __hip_bfloat16 bf16;

__device__ __forceinline__ int ufl(int v) { return __builtin_amdgcn_readfirstlane(v); }

// ---------- zero bucket counters ----------
__global__ void k_zero_bcnt(int* __restrict__ bcnt) {
    int i = blockIdx.x * 256 + threadIdx.x;
    if (i < NBUCK) bcnt[i] = 0;
}

// ---------- binning: bucket edges by dst>>8 into fixed-capacity bins ----------
__global__ __launch_bounds__(256) void k_bin(const int* __restrict__ src,
                                             const int* __restrict__ dst,
                                             int* __restrict__ bcnt,
                                             unsigned* __restrict__ bin) {
    __shared__ int hist[NBUCK];
    __shared__ int base[NBUCK];
    const int tid = threadIdx.x;
    for (int i = tid; i < NBUCK; i += 256) hist[i] = 0;
    const int e0 = blockIdx.x * EPB;

    unsigned rec[16];
    int bb[16];
#pragma unroll
    for (int j = 0; j < 16; ++j) {
        int e = e0 + tid + j * 256;
        if (e < N_EDGES) {
            int d = __builtin_nontemporal_load(dst + e);
            int s = __builtin_nontemporal_load(src + e);
            bb[j]  = d >> 8;
            rec[j] = (unsigned)s | ((unsigned)(d & 255) << 18);  // src < 2^18
        } else {
            bb[j] = -1;
        }
    }
    __syncthreads();
#pragma unroll
    for (int j = 0; j < 16; ++j)
        if (bb[j] >= 0) atomicAdd(&hist[bb[j]], 1);   // no return -> fire-and-forget
    __syncthreads();
    for (int i = tid; i < NBUCK; i += 256) {
        int c = hist[i];
        base[i] = c ? atomicAdd(&bcnt[i], c) : 0;
        hist[i] = 0;                       // reuse as local cursor
    }
    __syncthreads();
    int p[16];
#pragma unroll
    for (int j = 0; j < 16; ++j)
        if (bb[j] >= 0) p[j] = atomicAdd(&hist[bb[j]], 1);   // 16 independent rtn-atomics
#pragma unroll
    for (int j = 0; j < 16; ++j)
        if (bb[j] >= 0)
            bin[(size_t)bb[j] * BCAP + base[bb[j]] + p[j]] = rec[j];
}

// ---------- exclusive scan of 586 bucket counts (single block) ----------
__global__ __launch_bounds__(1024) void k_bscan(const int* __restrict__ bcnt,
                                                int* __restrict__ bbase) {
    __shared__ int sm[1024];
    int tid = threadIdx.x;
    int v = (tid < NBUCK) ? bcnt[tid] : 0;
    sm[tid] = v;
    __syncthreads();
    for (int off = 1; off < 1024; off <<= 1) {
        int t = (tid >= off) ? sm[tid - off] : 0;
        __syncthreads();
        sm[tid] += t;
        __syncthreads();
    }
    if (tid <= NBUCK) bbase[tid] = (tid == 0) ? 0 : sm[tid - 1];
}

// ---------- per-bucket: degree histogram -> rp, dis; scatter src-only CSR ----------
__global__ __launch_bounds__(256) void k_build(const unsigned* __restrict__ bin,
                                               const int* __restrict__ bcnt,
                                               const int* __restrict__ bbase,
                                               int* __restrict__ rp,
                                               float* __restrict__ dis,
                                               int* __restrict__ cws) {
    __shared__ int h[256];
    __shared__ int lc[256];
    const int tid   = threadIdx.x;
    const int b     = blockIdx.x;
    const int nbase = b << 8;
    const unsigned* mybin = bin + (size_t)b * BCAP;
    h[tid] = 0;
    __syncthreads();
    const int cnt  = bcnt[b];
    const int base = bbase[b];
    for (int i = tid; i < cnt; i += 256)
        atomicAdd(&h[__builtin_nontemporal_load(mybin + i) >> 18], 1);
    __syncthreads();
    int v = h[tid];
    // block exclusive scan of h
    __shared__ int sm[256];
    sm[tid] = v;
    __syncthreads();
    for (int off = 1; off < 256; off <<= 1) {
        int t = (tid >= off) ? sm[tid - off] : 0;
        __syncthreads();
        sm[tid] += t;
        __syncthreads();
    }
    int excl = sm[tid] - v;
    int n = nbase + tid;
    if (n < N_NODES) {
        rp[n]  = base + excl;
        dis[n] = (v > 0) ? rsqrtf((float)v) : 0.0f;
    }
    lc[tid] = base + excl;
    if (b == NBUCK - 1 && tid == 0) rp[N_NODES] = N_EDGES;
    __syncthreads();
    for (int i = tid; i < cnt; i += 256) {
        unsigned rec = __builtin_nontemporal_load(mybin + i);
        int dl = rec >> 18;
        int pos = atomicAdd(&lc[dl], 1);
        cws[pos] = (int)(rec & 0x3FFFF);
    }
}

// ---------- copy user_emb into emb0 (fp32) and y0 = bf16(dis*u) ----------
// acc init is no longer written: persistent spmm reads emb0 directly.
__global__ void k_copy_user(const float* __restrict__ u, const float* __restrict__ dis,
                            float* __restrict__ out, bf16* __restrict__ y) {
    int i = blockIdx.x * 256 + threadIdx.x;
    if (i < NUM_USERS * LATENT) {
        float v = __builtin_nontemporal_load(u + i);
        out[i] = v;                      // emb0
        float d = dis[i >> 6];           // wave-uniform
        y[i] = __float2bfloat16(d * v);  // layer-1 gather input (pre-scaled)
    }
}

// ---------- projection GEMM: 128x64 tile per block, K-tile 32; w transposed in LDS ----------
__global__ __launch_bounds__(256) void k_proj(const float* __restrict__ bert,
                                              const float* __restrict__ w,
                                              const float* __restrict__ dis,
                                              float* __restrict__ out,
                                              bf16* __restrict__ y) {
    __shared__ float sB[128][33];
    __shared__ float sW[32][64];
    const int tid  = threadIdx.x;
    const int rb   = blockIdx.x * 128;
    const int col8 = (tid & 7) * 8;
    const int rowg = (tid >> 3) * 4;

    float acc[4][8];
#pragma unroll
    for (int i = 0; i < 4; ++i)
#pragma unroll
        for (int j = 0; j < 8; ++j) acc[i][j] = 0.0f;

    for (int kb = 0; kb < SBERT; kb += 32) {
        __syncthreads();
#pragma unroll
        for (int j = 0; j < 4; ++j) {
            int idx = tid + j * 256;
            int r  = idx >> 3;
            int k4 = (idx & 7) * 4;
            int rr = min(rb + r, NUM_ITEMS - 1);
            const float* bp = bert + (size_t)rr * SBERT + kb + k4;
            float4 v = make_float4(__builtin_nontemporal_load(bp + 0),
                                   __builtin_nontemporal_load(bp + 1),
                                   __builtin_nontemporal_load(bp + 2),
                                   __builtin_nontemporal_load(bp + 3));
            sB[r][k4 + 0] = v.x; sB[r][k4 + 1] = v.y;
            sB[r][k4 + 2] = v.z; sB[r][k4 + 3] = v.w;
        }
#pragma unroll
        for (int j = 0; j < 2; ++j) {
            int idx = tid + j * 256;
            int c  = idx >> 3;
            int k4 = (idx & 7) * 4;
            float4 v = *(const float4*)(w + (size_t)c * SBERT + kb + k4);
            sW[k4 + 0][c] = v.x; sW[k4 + 1][c] = v.y;
            sW[k4 + 2][c] = v.z; sW[k4 + 3][c] = v.w;
        }
        __syncthreads();
#pragma unroll
        for (int kk = 0; kk < 32; ++kk) {
            float4 w0 = *(const float4*)&sW[kk][col8];
            float4 w1 = *(const float4*)&sW[kk][col8 + 4];
#pragma unroll
            for (int i = 0; i < 4; ++i) {
                float a = sB[rowg + i][kk];
                acc[i][0] = fmaf(a, w0.x, acc[i][0]);
                acc[i][1] = fmaf(a, w0.y, acc[i][1]);
                acc[i][2] = fmaf(a, w0.z, acc[i][2]);
                acc[i][3] = fmaf(a, w0.w, acc[i][3]);
                acc[i][4] = fmaf(a, w1.x, acc[i][4]);
                acc[i][5] = fmaf(a, w1.y, acc[i][5]);
                acc[i][6] = fmaf(a, w1.z, acc[i][6]);
                acc[i][7] = fmaf(a, w1.w, acc[i][7]);
            }
        }
    }
#pragma unroll
    for (int i = 0; i < 4; ++i) {
        int r = rb + rowg + i;
        if (r < NUM_ITEMS) {
            int n = NUM_USERS + r;
            size_t o = (size_t)n * LATENT + col8;
            float d = dis[n];
            float4 f0 = make_float4(acc[i][0], acc[i][1], acc[i][2], acc[i][3]);
            float4 f1 = make_float4(acc[i][4], acc[i][5], acc[i][6], acc[i][7]);
            *(float4*)(out + o)     = f0;        // emb0 only (no acc init)
            *(float4*)(out + o + 4) = f1;
#pragma unroll
            for (int j = 0; j < 8; ++j) y[o + j] = __float2bfloat16(d * acc[i][j]);
        }
    }
}

// ---------- persistent 3-layer SpMM: acc lives in VGPRs across all layers ----------
// Each wave owns nodes {w, w+4096, ...} (NPW=37, k=36 partial). acc read once
// (emb0), written once (x0.25). grid.sync() between layers. Numerically
// identical to the 3-launch path: same fp32 add order, same 16-deep grouping.
__global__ __launch_bounds__(256, 4) void k_spmm3(const bf16* __restrict__ ye,
                                                  bf16* __restrict__ y0,
                                                  bf16* __restrict__ y1,
                                                  const int* __restrict__ rp,
                                                  const int* __restrict__ cws,
                                                  const float* __restrict__ dis,
                                                  float* __restrict__ out) {
    cg::grid_group grid = cg::this_grid();
    const int lane = threadIdx.x & 63;
    const int w    = ufl(blockIdx.x * 4 + (threadIdx.x >> 6));   // wave id 0..4095

    float acc[NPW];
#pragma unroll
    for (int k = 0; k < NPW; ++k) {
        int node = w + (k << 12);
        acc[k] = (node < N_NODES) ? out[(size_t)node * LATENT + lane] : 0.0f;  // emb0
    }

    auto layer = [&](const bf16* __restrict__ ycur, bf16* __restrict__ ynext,
                     bool final_) {
#pragma unroll
        for (int k = 0; k < NPW; ++k) {
            int node = w + (k << 12);
            if (node < N_NODES) {
                int beg  = rp[node];
                int end  = rp[node + 1];
                int last = end - 1;
                float d  = dis[node];
                float a  = 0.0f;
                for (int base = beg; base < end; base += 16) {
                    int idx[16];
#pragma unroll
                    for (int j = 0; j < 16; ++j)
                        idx[j] = cws[min(base + j, last)];
                    float v[16];
#pragma unroll
                    for (int j = 0; j < 16; ++j)
                        v[j] = __bfloat162float(ycur[(size_t)idx[j] * LATENT + lane]);
#pragma unroll
                    for (int j = 0; j < 16; ++j)
                        if (base + j <= last) a += v[j];   // wave-uniform predicate
                }
                acc[k] += d * a;
                if (!final_)
                    ynext[(size_t)node * LATENT + lane] = __float2bfloat16(d * d * a);
            }
        }
    };

    layer(ye, y0, false);
    grid.sync();
    layer(y0, y1, false);
    grid.sync();
    layer(y1, nullptr, true);

#pragma unroll
    for (int k = 0; k < NPW; ++k) {
        int node = w + (k << 12);
        if (node < N_NODES)
            out[OUT_OFF + (size_t)node * LATENT + lane] = acc[k] * 0.25f;
    }
}

// ---------- fallback SpMM (3-launch), used if cooperative launch can't fit ----------
// FIRST: read acc-init from emb0 region (copy_user/proj no longer write acc).
template <bool FIRST, bool FINAL>
__global__ __launch_bounds__(256) void k_spmm(const bf16* __restrict__ y,
                                              const int* __restrict__ rp,
                                              const int* __restrict__ cws,
                                              const float* __restrict__ dis,
                                              bf16* __restrict__ yn,
                                              float* __restrict__ acc,
                                              const float* __restrict__ emb0) {
    int lane = threadIdx.x & 63;
    int node = ufl(blockIdx.x * 4 + (threadIdx.x >> 6));   // 37500*4 = 150000 exact
    int beg = rp[node];
    int end = rp[node + 1];
    int last = end - 1;
    float d = dis[node];
    size_t o = (size_t)node * LATENT + lane;
    float accv = FIRST ? emb0[o] : acc[o];
    float a = 0.0f;
    for (int base = beg; base < end; base += 16) {
        int idx[16];
#pragma unroll
        for (int j = 0; j < 16; ++j)
            idx[j] = cws[min(base + j, last)];
        float v[16];
#pragma unroll
        for (int j = 0; j < 16; ++j)
            v[j] = __bfloat162float(y[(size_t)idx[j] * LATENT + lane]);
#pragma unroll
        for (int j = 0; j < 16; ++j)
            if (base + j <= last) a += v[j];
    }
    if (!FINAL) yn[o] = __float2bfloat16(d * d * a);
    float t = accv + d * a;
    acc[o] = FINAL ? t * 0.25f : t;
}

extern "C" void kernel_launch(void* const* d_in, const int* in_sizes, int n_in,
                              void* d_out, int out_size, void* d_ws, size_t ws_size,
                              hipStream_t stream) {
    const int*   ei    = (const int*)d_in[0];
    const float* uemb  = (const float*)d_in[1];
    const float* bert  = (const float*)d_in[2];
    const float* wproj = (const float*)d_in[3];
    float* out = (float*)d_out;

    char* ws = (char*)d_ws;
    size_t off = 0;
    auto carve = [&](size_t bytes) -> void* {
        void* p = ws + off;
        off += (bytes + 255) & ~(size_t)255;
        return p;
    };
    float*    dis    = (float*)carve(sizeof(float) * N_NODES);
    int*      rp     = (int*)carve(sizeof(int) * (N_NODES + 1));
    int*      bcnt   = (int*)carve(sizeof(int) * NBUCK);
    int*      bbase  = (int*)carve(sizeof(int) * (NBUCK + 1));
    unsigned* bin    = (unsigned*)carve(sizeof(unsigned) * (size_t)NBUCK * BCAP);
    int*      cws    = (int*)carve(sizeof(int) * N_EDGES);
    bf16*     ye     = (bf16*)carve(sizeof(bf16) * (size_t)N_NODES * LATENT);
    bf16*     y0     = (bf16*)carve(sizeof(bf16) * (size_t)N_NODES * LATENT);
    bf16*     y1     = (bf16*)carve(sizeof(bf16) * (size_t)N_NODES * LATENT);

    const int* srcI = ei;
    const int* dstI = ei + N_EDGES;

    k_zero_bcnt<<<(NBUCK + 255) / 256, 256, 0, stream>>>(bcnt);
    k_bin<<<(N_EDGES + EPB - 1) / EPB, 256, 0, stream>>>(srcI, dstI, bcnt, bin);
    k_bscan<<<1, 1024, 0, stream>>>(bcnt, bbase);
    k_build<<<NBUCK, 256, 0, stream>>>(bin, bcnt, bbase, rp, dis, cws);
    k_copy_user<<<(NUM_USERS * LATENT + 255) / 256, 256, 0, stream>>>(uemb, dis, out, ye);
    k_proj<<<(NUM_ITEMS + 127) / 128, 256, 0, stream>>>(bert, wproj, dis, out, ye);

    float* accp = out + OUT_OFF;

    // Can the cooperative grid be fully co-resident? (checked once, host-side)
    static int coop_ok = -1;
    if (coop_ok < 0) {
        hipDeviceProp_t prop;
        int dev = 0;
        hipGetDevice(&dev);
        hipGetDeviceProperties(&prop, dev);
        int maxb = 0;
        hipError_t e = hipOccupancyMaxActiveBlocksPerMultiprocessor(
            &maxb, (const void*)k_spmm3, 256, 0);
        coop_ok = (e == hipSuccess && prop.cooperativeLaunch &&
                   maxb * prop.multiProcessorCount >= PBLK) ? 1 : 0;
    }

    if (coop_ok) {
        void* args[] = {(void*)&ye, (void*)&y0, (void*)&y1, (void*)&rp,
                        (void*)&cws, (void*)&dis, (void*)&out};
        hipLaunchCooperativeKernel((void*)k_spmm3, dim3(PBLK), dim3(256),
                                   args, 0, stream);
    } else {
        k_spmm<true,  false><<<N_NODES / 4, 256, 0, stream>>>(ye, rp, cws, dis, y0, accp, out);
        k_spmm<false, false><<<N_NODES / 4, 256, 0, stream>>>(y0, rp, cws, dis, y1, accp, out);
        k_spmm<false, true ><<<N_NODES / 4, 256, 0, stream>>>(y1, rp, cws, dis, y0, accp, out);
    }
}

// Round 6
// 434.479 us; speedup vs baseline: 1.2835x; 1.0133x over previous
//
#include <hip/hip_runtime.h>
#include <hip/hip_bf16.h>
#include <hip/hip_cooperative_groups.h>
#include <stdint.h>

namespace cg = cooperative_groups;

#define NUM_USERS 100000
#define NUM_ITEMS 50000
#define N_NODES   150000
#define LATENT    64
#define SBERT     384
#define N_EDGES   2000000
#define OUT_OFF   (N_NODES * LATENT)   // out = d_out + OUT_OFF
#define NBUCK     586                  // ceil(150000 / 256), 256 nodes per bucket
#define BCAP      4096                 // fixed bin capacity per bucket (mean 3413, sigma 58)
#define EPB       4096                 // edges per k_bin block (489 blocks, 16 edges/thread)
#define PBLK      2048                 // persistent grid: 8 blocks/CU * 256 CU = full residency
#define PWAVES    8192                 // PBLK * 4 waves
#define NPW       19                   // ceil(150000 / 8192) nodes per wave

typedef __hip_bfloat16 bf16;

__device__ __forceinline__ int ufl(int v) { return __builtin_amdgcn_readfirstlane(v); }

__device__ __forceinline__ unsigned short b16u(float f) {
    bf16 h = __float2bfloat16(f);
    return *reinterpret_cast<unsigned short*>(&h);
}

// ---------- zero bucket counters ----------
__global__ void k_zero_bcnt(int* __restrict__ bcnt) {
    int i = blockIdx.x * 256 + threadIdx.x;
    if (i < NBUCK) bcnt[i] = 0;
}

// ---------- binning: bucket edges by dst>>8 into fixed-capacity bins ----------
__global__ __launch_bounds__(256) void k_bin(const int* __restrict__ src,
                                             const int* __restrict__ dst,
                                             int* __restrict__ bcnt,
                                             unsigned* __restrict__ bin) {
    __shared__ int hist[NBUCK];
    __shared__ int base[NBUCK];
    const int tid = threadIdx.x;
    for (int i = tid; i < NBUCK; i += 256) hist[i] = 0;
    const int e0 = blockIdx.x * EPB;

    unsigned rec[16];
    int bb[16];
#pragma unroll
    for (int j = 0; j < 16; ++j) {
        int e = e0 + tid + j * 256;
        if (e < N_EDGES) {
            int d = __builtin_nontemporal_load(dst + e);
            int s = __builtin_nontemporal_load(src + e);
            bb[j]  = d >> 8;
            rec[j] = (unsigned)s | ((unsigned)(d & 255) << 18);  // src < 2^18
        } else {
            bb[j] = -1;
        }
    }
    __syncthreads();
#pragma unroll
    for (int j = 0; j < 16; ++j)
        if (bb[j] >= 0) atomicAdd(&hist[bb[j]], 1);   // no return -> fire-and-forget
    __syncthreads();
    for (int i = tid; i < NBUCK; i += 256) {
        int c = hist[i];
        base[i] = c ? atomicAdd(&bcnt[i], c) : 0;
        hist[i] = 0;                       // reuse as local cursor
    }
    __syncthreads();
    int p[16];
#pragma unroll
    for (int j = 0; j < 16; ++j)
        if (bb[j] >= 0) p[j] = atomicAdd(&hist[bb[j]], 1);   // 16 independent rtn-atomics
#pragma unroll
    for (int j = 0; j < 16; ++j)
        if (bb[j] >= 0)
            bin[(size_t)bb[j] * BCAP + base[bb[j]] + p[j]] = rec[j];
}

// ---------- exclusive scan of 586 bucket counts (single block) ----------
__global__ __launch_bounds__(1024) void k_bscan(const int* __restrict__ bcnt,
                                                int* __restrict__ bbase) {
    __shared__ int sm[1024];
    int tid = threadIdx.x;
    int v = (tid < NBUCK) ? bcnt[tid] : 0;
    sm[tid] = v;
    __syncthreads();
    for (int off = 1; off < 1024; off <<= 1) {
        int t = (tid >= off) ? sm[tid - off] : 0;
        __syncthreads();
        sm[tid] += t;
        __syncthreads();
    }
    if (tid <= NBUCK) bbase[tid] = (tid == 0) ? 0 : sm[tid - 1];
}

// ---------- per-bucket: degree histogram -> rp, dis; scatter src-only CSR ----------
__global__ __launch_bounds__(256) void k_build(const unsigned* __restrict__ bin,
                                               const int* __restrict__ bcnt,
                                               const int* __restrict__ bbase,
                                               int* __restrict__ rp,
                                               float* __restrict__ dis,
                                               int* __restrict__ cws) {
    __shared__ int h[256];
    __shared__ int lc[256];
    const int tid   = threadIdx.x;
    const int b     = blockIdx.x;
    const int nbase = b << 8;
    const unsigned* mybin = bin + (size_t)b * BCAP;
    h[tid] = 0;
    __syncthreads();
    const int cnt  = bcnt[b];
    const int base = bbase[b];
    for (int i = tid; i < cnt; i += 256)
        atomicAdd(&h[__builtin_nontemporal_load(mybin + i) >> 18], 1);
    __syncthreads();
    int v = h[tid];
    // block exclusive scan of h
    __shared__ int sm[256];
    sm[tid] = v;
    __syncthreads();
    for (int off = 1; off < 256; off <<= 1) {
        int t = (tid >= off) ? sm[tid - off] : 0;
        __syncthreads();
        sm[tid] += t;
        __syncthreads();
    }
    int excl = sm[tid] - v;
    int n = nbase + tid;
    if (n < N_NODES) {
        rp[n]  = base + excl;
        dis[n] = (v > 0) ? rsqrtf((float)v) : 0.0f;
    }
    lc[tid] = base + excl;
    if (b == NBUCK - 1 && tid == 0) rp[N_NODES] = N_EDGES;
    __syncthreads();
    for (int i = tid; i < cnt; i += 256) {
        unsigned rec = __builtin_nontemporal_load(mybin + i);
        int dl = rec >> 18;
        int pos = atomicAdd(&lc[dl], 1);
        cws[pos] = (int)(rec & 0x3FFFF);
    }
}

// ---------- copy user_emb into emb0 (fp32, float4) and y0 = bf16(dis*u) packed ----------
__global__ void k_copy_user(const float4* __restrict__ u4, const float* __restrict__ dis,
                            float4* __restrict__ out4, uint2* __restrict__ y2) {
    int i = blockIdx.x * 256 + threadIdx.x;          // float4 index; 100000*16 total
    if (i < NUM_USERS * 16) {
        float4 v = u4[i];
        out4[i] = v;                                 // emb0
        float d = dis[i >> 4];                       // 16 float4 per node
        uint2 p;
        p.x = (unsigned)b16u(d * v.x) | ((unsigned)b16u(d * v.y) << 16);
        p.y = (unsigned)b16u(d * v.z) | ((unsigned)b16u(d * v.w) << 16);
        y2[i] = p;                                   // 4 bf16 in 8 B
    }
}

// ---------- projection GEMM: 128x64 tile per block, K-tile 32; w transposed in LDS ----------
__global__ __launch_bounds__(256) void k_proj(const float* __restrict__ bert,
                                              const float* __restrict__ w,
                                              const float* __restrict__ dis,
                                              float* __restrict__ out,
                                              bf16* __restrict__ y) {
    __shared__ float sB[128][33];
    __shared__ float sW[32][64];
    const int tid  = threadIdx.x;
    const int rb   = blockIdx.x * 128;
    const int col8 = (tid & 7) * 8;
    const int rowg = (tid >> 3) * 4;

    float acc[4][8];
#pragma unroll
    for (int i = 0; i < 4; ++i)
#pragma unroll
        for (int j = 0; j < 8; ++j) acc[i][j] = 0.0f;

    for (int kb = 0; kb < SBERT; kb += 32) {
        __syncthreads();
#pragma unroll
        for (int j = 0; j < 4; ++j) {
            int idx = tid + j * 256;
            int r  = idx >> 3;
            int k4 = (idx & 7) * 4;
            int rr = min(rb + r, NUM_ITEMS - 1);
            const float* bp = bert + (size_t)rr * SBERT + kb + k4;
            float4 v = make_float4(__builtin_nontemporal_load(bp + 0),
                                   __builtin_nontemporal_load(bp + 1),
                                   __builtin_nontemporal_load(bp + 2),
                                   __builtin_nontemporal_load(bp + 3));
            sB[r][k4 + 0] = v.x; sB[r][k4 + 1] = v.y;
            sB[r][k4 + 2] = v.z; sB[r][k4 + 3] = v.w;
        }
#pragma unroll
        for (int j = 0; j < 2; ++j) {
            int idx = tid + j * 256;
            int c  = idx >> 3;
            int k4 = (idx & 7) * 4;
            float4 v = *(const float4*)(w + (size_t)c * SBERT + kb + k4);
            sW[k4 + 0][c] = v.x; sW[k4 + 1][c] = v.y;
            sW[k4 + 2][c] = v.z; sW[k4 + 3][c] = v.w;
        }
        __syncthreads();
#pragma unroll
        for (int kk = 0; kk < 32; ++kk) {
            float4 w0 = *(const float4*)&sW[kk][col8];
            float4 w1 = *(const float4*)&sW[kk][col8 + 4];
#pragma unroll
            for (int i = 0; i < 4; ++i) {
                float a = sB[rowg + i][kk];
                acc[i][0] = fmaf(a, w0.x, acc[i][0]);
                acc[i][1] = fmaf(a, w0.y, acc[i][1]);
                acc[i][2] = fmaf(a, w0.z, acc[i][2]);
                acc[i][3] = fmaf(a, w0.w, acc[i][3]);
                acc[i][4] = fmaf(a, w1.x, acc[i][4]);
                acc[i][5] = fmaf(a, w1.y, acc[i][5]);
                acc[i][6] = fmaf(a, w1.z, acc[i][6]);
                acc[i][7] = fmaf(a, w1.w, acc[i][7]);
            }
        }
    }
#pragma unroll
    for (int i = 0; i < 4; ++i) {
        int r = rb + rowg + i;
        if (r < NUM_ITEMS) {
            int n = NUM_USERS + r;
            size_t o = (size_t)n * LATENT + col8;
            float d = dis[n];
            float4 f0 = make_float4(acc[i][0], acc[i][1], acc[i][2], acc[i][3]);
            float4 f1 = make_float4(acc[i][4], acc[i][5], acc[i][6], acc[i][7]);
            *(float4*)(out + o)     = f0;        // emb0 only (no acc init)
            *(float4*)(out + o + 4) = f1;
#pragma unroll
            for (int j = 0; j < 8; ++j) y[o + j] = __float2bfloat16(d * acc[i][j]);
        }
    }
}

// ---------- persistent 3-layer SpMM: acc lives in VGPRs across all layers ----------
// 8192 waves (8 blocks/CU -> 100% residency), 19 nodes/wave. acc read once
// (emb0), written once (x0.25). grid.sync() between layers. Numerically
// identical to the 3-launch path: same fp32 add order, same 16-deep grouping.
__global__ __launch_bounds__(256, 8) void k_spmm3(const bf16* __restrict__ ye,
                                                  bf16* __restrict__ y0,
                                                  bf16* __restrict__ y1,
                                                  const int* __restrict__ rp,
                                                  const int* __restrict__ cws,
                                                  const float* __restrict__ dis,
                                                  float* __restrict__ out) {
    cg::grid_group grid = cg::this_grid();
    const int lane = threadIdx.x & 63;
    const int w    = ufl(blockIdx.x * 4 + (threadIdx.x >> 6));   // wave id 0..8191

    float acc[NPW];
#pragma unroll
    for (int k = 0; k < NPW; ++k) {
        int node = w + (k << 13);
        acc[k] = (node < N_NODES) ? out[(size_t)node * LATENT + lane] : 0.0f;  // emb0
    }

    auto layer = [&](const bf16* __restrict__ ycur, bf16* __restrict__ ynext,
                     bool final_) {
#pragma unroll
        for (int k = 0; k < NPW; ++k) {
            int node = w + (k << 13);
            if (node < N_NODES) {
                int beg  = rp[node];
                int end  = rp[node + 1];
                int last = end - 1;
                float d  = dis[node];
                float a  = 0.0f;
                for (int base = beg; base < end; base += 16) {
                    int idx[16];
#pragma unroll
                    for (int j = 0; j < 16; ++j)
                        idx[j] = cws[min(base + j, last)];
                    float v[16];
#pragma unroll
                    for (int j = 0; j < 16; ++j)
                        v[j] = __bfloat162float(ycur[(size_t)idx[j] * LATENT + lane]);
#pragma unroll
                    for (int j = 0; j < 16; ++j)
                        if (base + j <= last) a += v[j];   // wave-uniform predicate
                }
                acc[k] += d * a;
                if (!final_)
                    ynext[(size_t)node * LATENT + lane] = __float2bfloat16(d * d * a);
            }
        }
    };

    layer(ye, y0, false);
    grid.sync();
    layer(y0, y1, false);
    grid.sync();
    layer(y1, nullptr, true);

#pragma unroll
    for (int k = 0; k < NPW; ++k) {
        int node = w + (k << 13);
        if (node < N_NODES)
            out[OUT_OFF + (size_t)node * LATENT + lane] = acc[k] * 0.25f;
    }
}

// ---------- fallback SpMM (3-launch), used if cooperative launch can't fit ----------
template <bool FIRST, bool FINAL>
__global__ __launch_bounds__(256) void k_spmm(const bf16* __restrict__ y,
                                              const int* __restrict__ rp,
                                              const int* __restrict__ cws,
                                              const float* __restrict__ dis,
                                              bf16* __restrict__ yn,
                                              float* __restrict__ acc,
                                              const float* __restrict__ emb0) {
    int lane = threadIdx.x & 63;
    int node = ufl(blockIdx.x * 4 + (threadIdx.x >> 6));   // 37500*4 = 150000 exact
    int beg = rp[node];
    int end = rp[node + 1];
    int last = end - 1;
    float d = dis[node];
    size_t o = (size_t)node * LATENT + lane;
    float accv = FIRST ? emb0[o] : acc[o];
    float a = 0.0f;
    for (int base = beg; base < end; base += 16) {
        int idx[16];
#pragma unroll
        for (int j = 0; j < 16; ++j)
            idx[j] = cws[min(base + j, last)];
        float v[16];
#pragma unroll
        for (int j = 0; j < 16; ++j)
            v[j] = __bfloat162float(y[(size_t)idx[j] * LATENT + lane]);
#pragma unroll
        for (int j = 0; j < 16; ++j)
            if (base + j <= last) a += v[j];
    }
    if (!FINAL) yn[o] = __float2bfloat16(d * d * a);
    float t = accv + d * a;
    acc[o] = FINAL ? t * 0.25f : t;
}

extern "C" void kernel_launch(void* const* d_in, const int* in_sizes, int n_in,
                              void* d_out, int out_size, void* d_ws, size_t ws_size,
                              hipStream_t stream) {
    const int*   ei    = (const int*)d_in[0];
    const float* uemb  = (const float*)d_in[1];
    const float* bert  = (const float*)d_in[2];
    const float* wproj = (const float*)d_in[3];
    float* out = (float*)d_out;

    char* ws = (char*)d_ws;
    size_t off = 0;
    auto carve = [&](size_t bytes) -> void* {
        void* p = ws + off;
        off += (bytes + 255) & ~(size_t)255;
        return p;
    };
    float*    dis    = (float*)carve(sizeof(float) * N_NODES);
    int*      rp     = (int*)carve(sizeof(int) * (N_NODES + 1));
    int*      bcnt   = (int*)carve(sizeof(int) * NBUCK);
    int*      bbase  = (int*)carve(sizeof(int) * (NBUCK + 1));
    unsigned* bin    = (unsigned*)carve(sizeof(unsigned) * (size_t)NBUCK * BCAP);
    int*      cws    = (int*)carve(sizeof(int) * N_EDGES);
    bf16*     ye     = (bf16*)carve(sizeof(bf16) * (size_t)N_NODES * LATENT);
    bf16*     y0     = (bf16*)carve(sizeof(bf16) * (size_t)N_NODES * LATENT);
    bf16*     y1     = (bf16*)carve(sizeof(bf16) * (size_t)N_NODES * LATENT);

    const int* srcI = ei;
    const int* dstI = ei + N_EDGES;

    k_zero_bcnt<<<(NBUCK + 255) / 256, 256, 0, stream>>>(bcnt);
    k_bin<<<(N_EDGES + EPB - 1) / EPB, 256, 0, stream>>>(srcI, dstI, bcnt, bin);
    k_bscan<<<1, 1024, 0, stream>>>(bcnt, bbase);
    k_build<<<NBUCK, 256, 0, stream>>>(bin, bcnt, bbase, rp, dis, cws);
    k_copy_user<<<(NUM_USERS * 16 + 255) / 256, 256, 0, stream>>>(
        (const float4*)uemb, dis, (float4*)out, (uint2*)ye);
    k_proj<<<(NUM_ITEMS + 127) / 128, 256, 0, stream>>>(bert, wproj, dis, out, ye);

    float* accp = out + OUT_OFF;

    // Can the cooperative grid be fully co-resident? (checked once, host-side)
    static int coop_ok = -1;
    if (coop_ok < 0) {
        hipDeviceProp_t prop;
        int dev = 0;
        hipGetDevice(&dev);
        hipGetDeviceProperties(&prop, dev);
        int maxb = 0;
        hipError_t e = hipOccupancyMaxActiveBlocksPerMultiprocessor(
            &maxb, (const void*)k_spmm3, 256, 0);
        coop_ok = (e == hipSuccess && prop.cooperativeLaunch &&
                   maxb * prop.multiProcessorCount >= PBLK) ? 1 : 0;
    }

    if (coop_ok) {
        void* args[] = {(void*)&ye, (void*)&y0, (void*)&y1, (void*)&rp,
                        (void*)&cws, (void*)&dis, (void*)&out};
        hipLaunchCooperativeKernel((void*)k_spmm3, dim3(PBLK), dim3(256),
                                   args, 0, stream);
    } else {
        k_spmm<true,  false><<<N_NODES / 4, 256, 0, stream>>>(ye, rp, cws, dis, y0, accp, out);
        k_spmm<false, false><<<N_NODES / 4, 256, 0, stream>>>(y0, rp, cws, dis, y1, accp, out);
        k_spmm<false, true ><<<N_NODES / 4, 256, 0, stream>>>(y1, rp, cws, dis, y0, accp, out);
    }
}

// Round 7
// 433.303 us; speedup vs baseline: 1.2870x; 1.0027x over previous
//
#include <hip/hip_runtime.h>
#include <hip/hip_bf16.h>
#include <hip/hip_cooperative_groups.h>
#include <stdint.h>

namespace cg = cooperative_groups;

#define NUM_USERS 100000
#define NUM_ITEMS 50000
#define N_NODES   150000
#define LATENT    64
#define SBERT     384
#define N_EDGES   2000000
#define OUT_OFF   (N_NODES * LATENT)   // out = d_out + OUT_OFF
#define NBUCK     586                  // ceil(150000 / 256), 256 nodes per bucket
#define BCAP      4096                 // fixed bin capacity per bucket (mean 3413, sigma 58)
#define EPB       4096                 // edges per k_bin block (fallback path)

// ---- mega-kernel geometry ----
#define NBM       1536                 // 6 blocks/CU * 256 CU
#define EPBM      1303                 // ceil(N_EDGES / NBM); 6 edges/thread
#define WAVESM    6144                 // NBM * 4
#define NPWM      25                   // ceil(150000 / 6144) nodes per wave
#define PROJ_TILES 391                 // ceil(50000 / 128)

typedef __hip_bfloat16 bf16;

__device__ __forceinline__ int ufl(int v) { return __builtin_amdgcn_readfirstlane(v); }

__device__ __forceinline__ unsigned short b16u(float f) {
    bf16 h = __float2bfloat16(f);
    return *reinterpret_cast<unsigned short*>(&h);
}

// ===================== fallback-path kernels (proven, round-4 path) =====================

__global__ void k_zero_bcnt(int* __restrict__ bcnt) {
    int i = blockIdx.x * 256 + threadIdx.x;
    if (i < NBUCK) bcnt[i] = 0;
}

__global__ __launch_bounds__(256) void k_bin(const int* __restrict__ src,
                                             const int* __restrict__ dst,
                                             int* __restrict__ bcnt,
                                             unsigned* __restrict__ bin) {
    __shared__ int hist[NBUCK];
    __shared__ int base[NBUCK];
    const int tid = threadIdx.x;
    for (int i = tid; i < NBUCK; i += 256) hist[i] = 0;
    const int e0 = blockIdx.x * EPB;
    unsigned rec[16];
    int bb[16];
#pragma unroll
    for (int j = 0; j < 16; ++j) {
        int e = e0 + tid + j * 256;
        if (e < N_EDGES) {
            int d = __builtin_nontemporal_load(dst + e);
            int s = __builtin_nontemporal_load(src + e);
            bb[j]  = d >> 8;
            rec[j] = (unsigned)s | ((unsigned)(d & 255) << 18);
        } else bb[j] = -1;
    }
    __syncthreads();
#pragma unroll
    for (int j = 0; j < 16; ++j)
        if (bb[j] >= 0) atomicAdd(&hist[bb[j]], 1);
    __syncthreads();
    for (int i = tid; i < NBUCK; i += 256) {
        int c = hist[i];
        base[i] = c ? atomicAdd(&bcnt[i], c) : 0;
        hist[i] = 0;
    }
    __syncthreads();
    int p[16];
#pragma unroll
    for (int j = 0; j < 16; ++j)
        if (bb[j] >= 0) p[j] = atomicAdd(&hist[bb[j]], 1);
#pragma unroll
    for (int j = 0; j < 16; ++j)
        if (bb[j] >= 0)
            bin[(size_t)bb[j] * BCAP + base[bb[j]] + p[j]] = rec[j];
}

__global__ __launch_bounds__(1024) void k_bscan(const int* __restrict__ bcnt,
                                                int* __restrict__ bbase) {
    __shared__ int sm[1024];
    int tid = threadIdx.x;
    int v = (tid < NBUCK) ? bcnt[tid] : 0;
    sm[tid] = v;
    __syncthreads();
    for (int off = 1; off < 1024; off <<= 1) {
        int t = (tid >= off) ? sm[tid - off] : 0;
        __syncthreads();
        sm[tid] += t;
        __syncthreads();
    }
    if (tid <= NBUCK) bbase[tid] = (tid == 0) ? 0 : sm[tid - 1];
}

__global__ __launch_bounds__(256) void k_build(const unsigned* __restrict__ bin,
                                               const int* __restrict__ bcnt,
                                               const int* __restrict__ bbase,
                                               int* __restrict__ rp,
                                               float* __restrict__ dis,
                                               int* __restrict__ cws) {
    __shared__ int h[256];
    __shared__ int lc[256];
    __shared__ int sm[256];
    const int tid   = threadIdx.x;
    const int b     = blockIdx.x;
    const int nbase = b << 8;
    const unsigned* mybin = bin + (size_t)b * BCAP;
    h[tid] = 0;
    __syncthreads();
    const int cnt  = bcnt[b];
    const int base = bbase[b];
    for (int i = tid; i < cnt; i += 256)
        atomicAdd(&h[__builtin_nontemporal_load(mybin + i) >> 18], 1);
    __syncthreads();
    int v = h[tid];
    sm[tid] = v;
    __syncthreads();
    for (int off = 1; off < 256; off <<= 1) {
        int t = (tid >= off) ? sm[tid - off] : 0;
        __syncthreads();
        sm[tid] += t;
        __syncthreads();
    }
    int excl = sm[tid] - v;
    int n = nbase + tid;
    if (n < N_NODES) {
        rp[n]  = base + excl;
        dis[n] = (v > 0) ? rsqrtf((float)v) : 0.0f;
    }
    lc[tid] = base + excl;
    if (b == NBUCK - 1 && tid == 0) rp[N_NODES] = N_EDGES;
    __syncthreads();
    for (int i = tid; i < cnt; i += 256) {
        unsigned rec = __builtin_nontemporal_load(mybin + i);
        int dl = rec >> 18;
        int pos = atomicAdd(&lc[dl], 1);
        cws[pos] = (int)(rec & 0x3FFFF);
    }
}

__global__ void k_copy_user(const float4* __restrict__ u4, const float* __restrict__ dis,
                            float4* __restrict__ out4, uint2* __restrict__ y2) {
    int i = blockIdx.x * 256 + threadIdx.x;
    if (i < NUM_USERS * 16) {
        float4 v = u4[i];
        out4[i] = v;
        float d = dis[i >> 4];
        uint2 p;
        p.x = (unsigned)b16u(d * v.x) | ((unsigned)b16u(d * v.y) << 16);
        p.y = (unsigned)b16u(d * v.z) | ((unsigned)b16u(d * v.w) << 16);
        y2[i] = p;
    }
}

__global__ __launch_bounds__(256) void k_proj(const float* __restrict__ bert,
                                              const float* __restrict__ w,
                                              const float* __restrict__ dis,
                                              float* __restrict__ out,
                                              bf16* __restrict__ y) {
    __shared__ float sB[128][33];
    __shared__ float sW[32][64];
    const int tid  = threadIdx.x;
    const int rb   = blockIdx.x * 128;
    const int col8 = (tid & 7) * 8;
    const int rowg = (tid >> 3) * 4;
    float acc[4][8];
#pragma unroll
    for (int i = 0; i < 4; ++i)
#pragma unroll
        for (int j = 0; j < 8; ++j) acc[i][j] = 0.0f;
    for (int kb = 0; kb < SBERT; kb += 32) {
        __syncthreads();
#pragma unroll
        for (int j = 0; j < 4; ++j) {
            int idx = tid + j * 256;
            int r  = idx >> 3;
            int k4 = (idx & 7) * 4;
            int rr = min(rb + r, NUM_ITEMS - 1);
            const float* bp = bert + (size_t)rr * SBERT + kb + k4;
            sB[r][k4 + 0] = __builtin_nontemporal_load(bp + 0);
            sB[r][k4 + 1] = __builtin_nontemporal_load(bp + 1);
            sB[r][k4 + 2] = __builtin_nontemporal_load(bp + 2);
            sB[r][k4 + 3] = __builtin_nontemporal_load(bp + 3);
        }
#pragma unroll
        for (int j = 0; j < 2; ++j) {
            int idx = tid + j * 256;
            int c  = idx >> 3;
            int k4 = (idx & 7) * 4;
            float4 v = *(const float4*)(w + (size_t)c * SBERT + kb + k4);
            sW[k4 + 0][c] = v.x; sW[k4 + 1][c] = v.y;
            sW[k4 + 2][c] = v.z; sW[k4 + 3][c] = v.w;
        }
        __syncthreads();
#pragma unroll
        for (int kk = 0; kk < 32; ++kk) {
            float4 w0 = *(const float4*)&sW[kk][col8];
            float4 w1 = *(const float4*)&sW[kk][col8 + 4];
#pragma unroll
            for (int i = 0; i < 4; ++i) {
                float a = sB[rowg + i][kk];
                acc[i][0] = fmaf(a, w0.x, acc[i][0]);
                acc[i][1] = fmaf(a, w0.y, acc[i][1]);
                acc[i][2] = fmaf(a, w0.z, acc[i][2]);
                acc[i][3] = fmaf(a, w0.w, acc[i][3]);
                acc[i][4] = fmaf(a, w1.x, acc[i][4]);
                acc[i][5] = fmaf(a, w1.y, acc[i][5]);
                acc[i][6] = fmaf(a, w1.z, acc[i][6]);
                acc[i][7] = fmaf(a, w1.w, acc[i][7]);
            }
        }
    }
#pragma unroll
    for (int i = 0; i < 4; ++i) {
        int r = rb + rowg + i;
        if (r < NUM_ITEMS) {
            int n = NUM_USERS + r;
            size_t o = (size_t)n * LATENT + col8;
            float d = dis[n];
            float4 f0 = make_float4(acc[i][0], acc[i][1], acc[i][2], acc[i][3]);
            float4 f1 = make_float4(acc[i][4], acc[i][5], acc[i][6], acc[i][7]);
            *(float4*)(out + o)     = f0;
            *(float4*)(out + o + 4) = f1;
#pragma unroll
            for (int j = 0; j < 8; ++j) y[o + j] = __float2bfloat16(d * acc[i][j]);
        }
    }
}

template <bool FIRST, bool FINAL>
__global__ __launch_bounds__(256) void k_spmm(const bf16* __restrict__ y,
                                              const int* __restrict__ rp,
                                              const int* __restrict__ cws,
                                              const float* __restrict__ dis,
                                              bf16* __restrict__ yn,
                                              float* __restrict__ acc,
                                              const float* __restrict__ emb0) {
    int lane = threadIdx.x & 63;
    int node = ufl(blockIdx.x * 4 + (threadIdx.x >> 6));
    int beg = rp[node];
    int end = rp[node + 1];
    int last = end - 1;
    float d = dis[node];
    size_t o = (size_t)node * LATENT + lane;
    float accv = FIRST ? emb0[o] : acc[o];
    float a = 0.0f;
    for (int base = beg; base < end; base += 16) {
        int idx[16];
#pragma unroll
        for (int j = 0; j < 16; ++j)
            idx[j] = cws[min(base + j, last)];
        float v[16];
#pragma unroll
        for (int j = 0; j < 16; ++j)
            v[j] = __bfloat162float(y[(size_t)idx[j] * LATENT + lane]);
#pragma unroll
        for (int j = 0; j < 16; ++j)
            if (base + j <= last) a += v[j];
    }
    if (!FINAL) yn[o] = __float2bfloat16(d * d * a);
    float t = accv + d * a;
    acc[o] = FINAL ? t * 0.25f : t;
}

// ===================== the mega cooperative kernel =====================
// Entire pipeline in one dispatch; grid.sync() replaces kernel boundaries.
// Each phase is the verified standalone body with blockIdx remapped.

struct SMbin   { int hist[NBUCK]; int base[NBUCK]; };
struct SMscan  { int a[640]; int b[640]; };
struct SMbuild { int h[256]; int lc[256]; int sm[256]; };
struct SMproj  { float sB[128][33]; float sW[32][64]; };
union  SMu { SMbin bin; SMscan scan; SMbuild build; SMproj proj; };

__global__ __launch_bounds__(256, 6) void k_mega(const int* __restrict__ srcI,
                                                 const int* __restrict__ dstI,
                                                 const float* __restrict__ uemb,
                                                 const float* __restrict__ bert,
                                                 const float* __restrict__ wproj,
                                                 int* __restrict__ bcnt,
                                                 int* __restrict__ bbase,
                                                 unsigned* __restrict__ bin,
                                                 int* __restrict__ rp,
                                                 float* __restrict__ dis,
                                                 int* __restrict__ cws,
                                                 bf16* __restrict__ ye,
                                                 bf16* __restrict__ y0,
                                                 bf16* __restrict__ y1,
                                                 float* __restrict__ out) {
    cg::grid_group grid = cg::this_grid();
    __shared__ SMu smu;
    const int tid = threadIdx.x;
    const int bid = blockIdx.x;

    // ---- P0: zero bucket counters ----
    {
        int i = bid * 256 + tid;
        if (i < NBUCK) bcnt[i] = 0;
    }
    grid.sync();

    // ---- P1: bin (one EPBM chunk per block) ----
    {
        for (int i = tid; i < NBUCK; i += 256) smu.bin.hist[i] = 0;
        const int e0 = bid * EPBM;
        const int e1 = min(e0 + EPBM, N_EDGES);
        unsigned rec[6];
        int bb[6];
#pragma unroll
        for (int j = 0; j < 6; ++j) {
            int e = e0 + tid + j * 256;
            if (e < e1) {
                int d = __builtin_nontemporal_load(dstI + e);
                int s = __builtin_nontemporal_load(srcI + e);
                bb[j]  = d >> 8;
                rec[j] = (unsigned)s | ((unsigned)(d & 255) << 18);
            } else bb[j] = -1;
        }
        __syncthreads();
#pragma unroll
        for (int j = 0; j < 6; ++j)
            if (bb[j] >= 0) atomicAdd(&smu.bin.hist[bb[j]], 1);
        __syncthreads();
        for (int i = tid; i < NBUCK; i += 256) {
            int c = smu.bin.hist[i];
            smu.bin.base[i] = c ? atomicAdd(&bcnt[i], c) : 0;
            smu.bin.hist[i] = 0;
        }
        __syncthreads();
        int p[6];
#pragma unroll
        for (int j = 0; j < 6; ++j)
            if (bb[j] >= 0) p[j] = atomicAdd(&smu.bin.hist[bb[j]], 1);
#pragma unroll
        for (int j = 0; j < 6; ++j)
            if (bb[j] >= 0)
                bin[(size_t)bb[j] * BCAP + smu.bin.base[bb[j]] + p[j]] = rec[j];
    }
    grid.sync();

    // ---- P2: scan bucket counts (block 0 only; Hillis-Steele, double-buffered) ----
    if (bid == 0) {
        int* A = smu.scan.a;
        int* B = smu.scan.b;
        for (int i = tid; i < NBUCK; i += 256) A[i] = bcnt[i];
        __syncthreads();
        for (int off = 1; off < NBUCK; off <<= 1) {
            for (int i = tid; i < NBUCK; i += 256)
                B[i] = (i >= off) ? A[i] + A[i - off] : A[i];
            __syncthreads();
            int* t = A; A = B; B = t;
        }
        for (int i = tid; i <= NBUCK; i += 256)
            bbase[i] = (i == 0) ? 0 : A[i - 1];
    }
    grid.sync();

    // ---- P3: build per-bucket CSR (blocks 0..585) ----
    if (bid < NBUCK) {
        const int nbase = bid << 8;
        const unsigned* mybin = bin + (size_t)bid * BCAP;
        smu.build.h[tid] = 0;
        __syncthreads();
        const int cnt  = bcnt[bid];
        const int base = bbase[bid];
        for (int i = tid; i < cnt; i += 256)
            atomicAdd(&smu.build.h[__builtin_nontemporal_load(mybin + i) >> 18], 1);
        __syncthreads();
        int v = smu.build.h[tid];
        smu.build.sm[tid] = v;
        __syncthreads();
        for (int off = 1; off < 256; off <<= 1) {
            int t = (tid >= off) ? smu.build.sm[tid - off] : 0;
            __syncthreads();
            smu.build.sm[tid] += t;
            __syncthreads();
        }
        int excl = smu.build.sm[tid] - v;
        int n = nbase + tid;
        if (n < N_NODES) {
            rp[n]  = base + excl;
            dis[n] = (v > 0) ? rsqrtf((float)v) : 0.0f;
        }
        smu.build.lc[tid] = base + excl;
        if (bid == NBUCK - 1 && tid == 0) rp[N_NODES] = N_EDGES;
        __syncthreads();
        for (int i = tid; i < cnt; i += 256) {
            unsigned rec = __builtin_nontemporal_load(mybin + i);
            int dl = rec >> 18;
            int pos = atomicAdd(&smu.build.lc[dl], 1);
            cws[pos] = (int)(rec & 0x3FFFF);
        }
    }
    grid.sync();

    // ---- P4: copy_user (grid-stride) + proj (blocks 0..390); disjoint outputs ----
    {
        const float4* u4  = (const float4*)uemb;
        float4* out4      = (float4*)out;
        uint2* y2         = (uint2*)ye;
        for (int i = bid * 256 + tid; i < NUM_USERS * 16; i += NBM * 256) {
            float4 v = u4[i];
            out4[i] = v;
            float d = dis[i >> 4];
            uint2 p;
            p.x = (unsigned)b16u(d * v.x) | ((unsigned)b16u(d * v.y) << 16);
            p.y = (unsigned)b16u(d * v.z) | ((unsigned)b16u(d * v.w) << 16);
            y2[i] = p;
        }
    }
    if (bid < PROJ_TILES) {
        const int rb   = bid * 128;
        const int col8 = (tid & 7) * 8;
        const int rowg = (tid >> 3) * 4;
        float acc[4][8];
#pragma unroll
        for (int i = 0; i < 4; ++i)
#pragma unroll
            for (int j = 0; j < 8; ++j) acc[i][j] = 0.0f;
        for (int kb = 0; kb < SBERT; kb += 32) {
            __syncthreads();
#pragma unroll
            for (int j = 0; j < 4; ++j) {
                int idx = tid + j * 256;
                int r  = idx >> 3;
                int k4 = (idx & 7) * 4;
                int rr = min(rb + r, NUM_ITEMS - 1);
                const float* bp = bert + (size_t)rr * SBERT + kb + k4;
                smu.proj.sB[r][k4 + 0] = __builtin_nontemporal_load(bp + 0);
                smu.proj.sB[r][k4 + 1] = __builtin_nontemporal_load(bp + 1);
                smu.proj.sB[r][k4 + 2] = __builtin_nontemporal_load(bp + 2);
                smu.proj.sB[r][k4 + 3] = __builtin_nontemporal_load(bp + 3);
            }
#pragma unroll
            for (int j = 0; j < 2; ++j) {
                int idx = tid + j * 256;
                int c  = idx >> 3;
                int k4 = (idx & 7) * 4;
                float4 v = *(const float4*)(wproj + (size_t)c * SBERT + kb + k4);
                smu.proj.sW[k4 + 0][c] = v.x; smu.proj.sW[k4 + 1][c] = v.y;
                smu.proj.sW[k4 + 2][c] = v.z; smu.proj.sW[k4 + 3][c] = v.w;
            }
            __syncthreads();
#pragma unroll
            for (int kk = 0; kk < 32; ++kk) {
                float4 w0 = *(const float4*)&smu.proj.sW[kk][col8];
                float4 w1 = *(const float4*)&smu.proj.sW[kk][col8 + 4];
#pragma unroll
                for (int i = 0; i < 4; ++i) {
                    float a = smu.proj.sB[rowg + i][kk];
                    acc[i][0] = fmaf(a, w0.x, acc[i][0]);
                    acc[i][1] = fmaf(a, w0.y, acc[i][1]);
                    acc[i][2] = fmaf(a, w0.z, acc[i][2]);
                    acc[i][3] = fmaf(a, w0.w, acc[i][3]);
                    acc[i][4] = fmaf(a, w1.x, acc[i][4]);
                    acc[i][5] = fmaf(a, w1.y, acc[i][5]);
                    acc[i][6] = fmaf(a, w1.z, acc[i][6]);
                    acc[i][7] = fmaf(a, w1.w, acc[i][7]);
                }
            }
        }
#pragma unroll
        for (int i = 0; i < 4; ++i) {
            int r = rb + rowg + i;
            if (r < NUM_ITEMS) {
                int n = NUM_USERS + r;
                size_t o = (size_t)n * LATENT + col8;
                float d = dis[n];
                float4 f0 = make_float4(acc[i][0], acc[i][1], acc[i][2], acc[i][3]);
                float4 f1 = make_float4(acc[i][4], acc[i][5], acc[i][6], acc[i][7]);
                *(float4*)(out + o)     = f0;
                *(float4*)(out + o + 4) = f1;
#pragma unroll
                for (int j = 0; j < 8; ++j) ye[o + j] = __float2bfloat16(d * acc[i][j]);
            }
        }
    }
    grid.sync();

    // ---- P5-P7: 3 SpMM layers, acc resident in registers ----
    {
        const int lane = tid & 63;
        const int w    = ufl(bid * 4 + (tid >> 6));      // wave id 0..6143
        float acc[NPWM];
#pragma unroll
        for (int k = 0; k < NPWM; ++k) {
            int node = w + k * WAVESM;
            acc[k] = (node < N_NODES) ? out[(size_t)node * LATENT + lane] : 0.0f;
        }
        auto layer = [&](const bf16* __restrict__ ycur, bf16* __restrict__ ynext,
                         bool final_) {
#pragma unroll
            for (int k = 0; k < NPWM; ++k) {
                int node = w + k * WAVESM;
                if (node < N_NODES) {
                    int beg  = rp[node];
                    int end  = rp[node + 1];
                    int last = end - 1;
                    float d  = dis[node];
                    float a  = 0.0f;
                    for (int base = beg; base < end; base += 16) {
                        int idx[16];
#pragma unroll
                        for (int j = 0; j < 16; ++j)
                            idx[j] = cws[min(base + j, last)];
                        float v[16];
#pragma unroll
                        for (int j = 0; j < 16; ++j)
                            v[j] = __bfloat162float(ycur[(size_t)idx[j] * LATENT + lane]);
#pragma unroll
                        for (int j = 0; j < 16; ++j)
                            if (base + j <= last) a += v[j];
                    }
                    acc[k] += d * a;
                    if (!final_)
                        ynext[(size_t)node * LATENT + lane] = __float2bfloat16(d * d * a);
                }
            }
        };
        layer(ye, y0, false);
        grid.sync();
        layer(y0, y1, false);
        grid.sync();
        layer(y1, nullptr, true);
#pragma unroll
        for (int k = 0; k < NPWM; ++k) {
            int node = w + k * WAVESM;
            if (node < N_NODES)
                out[OUT_OFF + (size_t)node * LATENT + lane] = acc[k] * 0.25f;
        }
    }
}

extern "C" void kernel_launch(void* const* d_in, const int* in_sizes, int n_in,
                              void* d_out, int out_size, void* d_ws, size_t ws_size,
                              hipStream_t stream) {
    const int*   ei    = (const int*)d_in[0];
    const float* uemb  = (const float*)d_in[1];
    const float* bert  = (const float*)d_in[2];
    const float* wproj = (const float*)d_in[3];
    float* out = (float*)d_out;

    char* ws = (char*)d_ws;
    size_t off = 0;
    auto carve = [&](size_t bytes) -> void* {
        void* p = ws + off;
        off += (bytes + 255) & ~(size_t)255;
        return p;
    };
    float*    dis    = (float*)carve(sizeof(float) * N_NODES);
    int*      rp     = (int*)carve(sizeof(int) * (N_NODES + 1));
    int*      bcnt   = (int*)carve(sizeof(int) * NBUCK);
    int*      bbase  = (int*)carve(sizeof(int) * (NBUCK + 1));
    unsigned* bin    = (unsigned*)carve(sizeof(unsigned) * (size_t)NBUCK * BCAP);
    int*      cws    = (int*)carve(sizeof(int) * N_EDGES);
    bf16*     ye     = (bf16*)carve(sizeof(bf16) * (size_t)N_NODES * LATENT);
    bf16*     y0     = (bf16*)carve(sizeof(bf16) * (size_t)N_NODES * LATENT);
    bf16*     y1     = (bf16*)carve(sizeof(bf16) * (size_t)N_NODES * LATENT);

    const int* srcI = ei;
    const int* dstI = ei + N_EDGES;

    // Can the mega cooperative grid be fully co-resident? (host-side, once)
    static int coop_ok = -1;
    if (coop_ok < 0) {
        hipDeviceProp_t prop;
        int dev = 0;
        hipGetDevice(&dev);
        hipGetDeviceProperties(&prop, dev);
        int maxb = 0;
        hipError_t e = hipOccupancyMaxActiveBlocksPerMultiprocessor(
            &maxb, (const void*)k_mega, 256, 0);
        coop_ok = (e == hipSuccess && prop.cooperativeLaunch &&
                   maxb * prop.multiProcessorCount >= NBM) ? 1 : 0;
    }

    if (coop_ok) {
        void* args[] = {(void*)&srcI, (void*)&dstI, (void*)&uemb, (void*)&bert,
                        (void*)&wproj, (void*)&bcnt, (void*)&bbase, (void*)&bin,
                        (void*)&rp, (void*)&dis, (void*)&cws, (void*)&ye,
                        (void*)&y0, (void*)&y1, (void*)&out};
        hipLaunchCooperativeKernel((void*)k_mega, dim3(NBM), dim3(256),
                                   args, 0, stream);
    } else {
        // proven multi-kernel fallback (round-4 path)
        k_zero_bcnt<<<(NBUCK + 255) / 256, 256, 0, stream>>>(bcnt);
        k_bin<<<(N_EDGES + EPB - 1) / EPB, 256, 0, stream>>>(srcI, dstI, bcnt, bin);
        k_bscan<<<1, 1024, 0, stream>>>(bcnt, bbase);
        k_build<<<NBUCK, 256, 0, stream>>>(bin, bcnt, bbase, rp, dis, cws);
        k_copy_user<<<(NUM_USERS * 16 + 255) / 256, 256, 0, stream>>>(
            (const float4*)uemb, dis, (float4*)out, (uint2*)ye);
        k_proj<<<(NUM_ITEMS + 127) / 128, 256, 0, stream>>>(bert, wproj, dis, out, ye);
        float* accp = out + OUT_OFF;
        k_spmm<true,  false><<<N_NODES / 4, 256, 0, stream>>>(ye, rp, cws, dis, y0, accp, out);
        k_spmm<false, false><<<N_NODES / 4, 256, 0, stream>>>(y0, rp, cws, dis, y1, accp, out);
        k_spmm<false, true ><<<N_NODES / 4, 256, 0, stream>>>(y1, rp, cws, dis, y0, accp, out);
    }
}